// Round 2
// baseline (2887.144 us; speedup 1.0000x reference)
//
#include <hip/hip_runtime.h>

#define Nn 50000
#define Ee 800000
#define HD 128        // D == H == 128
#define Ll 3
#define Gg 128
#define Cc 10
#define BN_EPS 1e-5f

// ----------------------------- CSR build ------------------------------------
__global__ void k_deg(const int* __restrict__ dst, int* __restrict__ deg) {
  int i = blockIdx.x * blockDim.x + threadIdx.x;
  int stride = gridDim.x * blockDim.x;
  for (int e = i; e < Ee; e += stride) atomicAdd(&deg[dst[e]], 1);
}

// single-block exclusive scan over deg[Nn] -> offs[Nn+1], copy to cursor
__global__ void k_scan(const int* __restrict__ deg, int* __restrict__ offs,
                       int* __restrict__ cursor) {
  __shared__ int b0[1024], b1[1024];
  __shared__ int carry;
  int tid = threadIdx.x;
  if (tid == 0) carry = 0;
  __syncthreads();
  const int ntile = (Nn + 1023) >> 10;
  for (int t = 0; t < ntile; ++t) {
    int i = (t << 10) + tid;
    int v = (i < Nn) ? deg[i] : 0;
    int* cur = b0; int* nxt = b1;
    cur[tid] = v;
    __syncthreads();
    for (int off = 1; off < 1024; off <<= 1) {
      int s = cur[tid] + ((tid >= off) ? cur[tid - off] : 0);
      nxt[tid] = s;
      __syncthreads();
      int* tmp = cur; cur = nxt; nxt = tmp;
    }
    int incl = cur[tid];
    int tot  = cur[1023];
    int excl = incl - v + carry;
    if (i < Nn) { offs[i] = excl; cursor[i] = excl; }
    __syncthreads();
    if (tid == 0) carry += tot;
    __syncthreads();
  }
  if (tid == 0) offs[Nn] = carry;   // == Ee
}

__global__ void k_fill(const int* __restrict__ src, const int* __restrict__ dst,
                       const float* __restrict__ ec, int* __restrict__ cursor,
                       int* __restrict__ esrc, float* __restrict__ ew) {
  int i = blockIdx.x * blockDim.x + threadIdx.x;
  int stride = gridDim.x * blockDim.x;
  for (int e = i; e < Ee; e += stride) {
    int d = dst[e];
    int p = atomicAdd(&cursor[d], 1);
    esrc[p] = src[e];
    ew[p]   = ec[e];
  }
}

// -------------------- aggregation: gather (one wave per node) ---------------
__global__ void k_agg(const float* __restrict__ xin, const int* __restrict__ offs,
                      const int* __restrict__ esrc, const float* __restrict__ ew,
                      float* __restrict__ agg) {
  int wid = threadIdx.x >> 6, lane = threadIdx.x & 63;
  int n = blockIdx.x * 4 + wid;
  if (n >= Nn) return;
  int beg = offs[n], end = offs[n + 1];
  const float2* x2 = (const float2*)xin;
  float2 acc = make_float2(0.f, 0.f);
  for (int j = beg; j < end; ++j) {
    int s = esrc[j];
    float w = ew[j];
    float2 v = x2[s * 64 + lane];
    acc.x = fmaf(v.x, w, acc.x);
    acc.y = fmaf(v.y, w, acc.y);
  }
  ((float2*)agg)[n * 64 + lane] = acc;
}

// -------------------- GEMM1: h1 = (agg*nc + x) @ W1 + b1, + BN stats --------
// 64-row tile, 256 threads, thread computes 8 rows x 4 cols. K=128 fully in LDS.
__launch_bounds__(256)
__global__ void k_gemm1(const float* __restrict__ agg, const float* __restrict__ nc,
                        const float* __restrict__ xin, const float* __restrict__ W,
                        const float* __restrict__ bias, float* __restrict__ out,
                        float* __restrict__ colsum, float* __restrict__ colsumsq) {
  __shared__ float Als[64][132];       // row-major, padded stride
  __shared__ float4 Wls[128 * 32];     // [k][col4]
  int tid = threadIdx.x;
  int row0 = blockIdx.x * 64;

  const float4* Wf4 = (const float4*)W;
  for (int i = tid; i < 4096; i += 256) Wls[i] = Wf4[i];

  int c4 = tid & 31, rr = tid >> 5;
  for (int it = 0; it < 8; ++it) {
    int r = rr + it * 8;
    int grow = row0 + r;
    float4 a = make_float4(0.f, 0.f, 0.f, 0.f);
    if (grow < Nn) {
      float4 ag = ((const float4*)agg)[grow * 32 + c4];
      float4 xv = ((const float4*)xin)[grow * 32 + c4];
      float nv = nc[grow];
      a.x = fmaf(ag.x, nv, xv.x); a.y = fmaf(ag.y, nv, xv.y);
      a.z = fmaf(ag.z, nv, xv.z); a.w = fmaf(ag.w, nv, xv.w);
    }
    *(float4*)&Als[r][c4 * 4] = a;
  }
  __syncthreads();

  int tx = tid & 31, ty = tid >> 5;
  float acc[8][4];
#pragma unroll
  for (int i = 0; i < 8; ++i)
#pragma unroll
    for (int j = 0; j < 4; ++j) acc[i][j] = 0.f;

#pragma unroll 4
  for (int k0 = 0; k0 < 128; k0 += 4) {
    float4 b0 = Wls[(k0 + 0) * 32 + tx];
    float4 b1v = Wls[(k0 + 1) * 32 + tx];
    float4 b2v = Wls[(k0 + 2) * 32 + tx];
    float4 b3v = Wls[(k0 + 3) * 32 + tx];
#pragma unroll
    for (int i = 0; i < 8; ++i) {
      float4 av = *(const float4*)&Als[ty * 8 + i][k0];
      acc[i][0] = fmaf(av.x, b0.x, acc[i][0]); acc[i][1] = fmaf(av.x, b0.y, acc[i][1]);
      acc[i][2] = fmaf(av.x, b0.z, acc[i][2]); acc[i][3] = fmaf(av.x, b0.w, acc[i][3]);
      acc[i][0] = fmaf(av.y, b1v.x, acc[i][0]); acc[i][1] = fmaf(av.y, b1v.y, acc[i][1]);
      acc[i][2] = fmaf(av.y, b1v.z, acc[i][2]); acc[i][3] = fmaf(av.y, b1v.w, acc[i][3]);
      acc[i][0] = fmaf(av.z, b2v.x, acc[i][0]); acc[i][1] = fmaf(av.z, b2v.y, acc[i][1]);
      acc[i][2] = fmaf(av.z, b2v.z, acc[i][2]); acc[i][3] = fmaf(av.z, b2v.w, acc[i][3]);
      acc[i][0] = fmaf(av.w, b3v.x, acc[i][0]); acc[i][1] = fmaf(av.w, b3v.y, acc[i][1]);
      acc[i][2] = fmaf(av.w, b3v.z, acc[i][2]); acc[i][3] = fmaf(av.w, b3v.w, acc[i][3]);
    }
  }

  float4 bcol = ((const float4*)bias)[tx];
  float s0 = 0, s1 = 0, s2 = 0, s3 = 0, q0 = 0, q1 = 0, q2 = 0, q3 = 0;
#pragma unroll
  for (int i = 0; i < 8; ++i) {
    int grow = row0 + ty * 8 + i;
    if (grow < Nn) {
      float4 o;
      o.x = acc[i][0] + bcol.x; o.y = acc[i][1] + bcol.y;
      o.z = acc[i][2] + bcol.z; o.w = acc[i][3] + bcol.w;
      ((float4*)out)[grow * 32 + tx] = o;
      s0 += o.x; s1 += o.y; s2 += o.z; s3 += o.w;
      q0 += o.x * o.x; q1 += o.y * o.y; q2 += o.z * o.z; q3 += o.w * o.w;
    }
  }
  atomicAdd(&colsum[tx * 4 + 0], s0); atomicAdd(&colsum[tx * 4 + 1], s1);
  atomicAdd(&colsum[tx * 4 + 2], s2); atomicAdd(&colsum[tx * 4 + 3], s3);
  atomicAdd(&colsumsq[tx * 4 + 0], q0); atomicAdd(&colsumsq[tx * 4 + 1], q1);
  atomicAdd(&colsumsq[tx * 4 + 2], q2); atomicAdd(&colsumsq[tx * 4 + 3], q3);
}

// finalize BN affine: scaleA = rsqrt(var+eps)*g1 ; shiftA = be1 - mu*scaleA
__global__ void k_bnfin(const float* __restrict__ colsum, const float* __restrict__ colsumsq,
                        const float* __restrict__ g1, const float* __restrict__ be1,
                        float* __restrict__ scaleA, float* __restrict__ shiftA) {
  int f = threadIdx.x;
  float s = colsum[f], q = colsumsq[f];
  const float inv = 1.0f / (float)Nn;
  float mu = s * inv;
  float var = fmaxf(q * inv - mu * mu, 0.f);
  float rs = rsqrtf(var + BN_EPS);
  float sc = rs * g1[f];
  scaleA[f] = sc;
  shiftA[f] = be1[f] - mu * sc;
}

// -------- GEMM2: xout = relu( relu(h1*scaleA+shiftA) @ W2 + b2 ) ------------
__launch_bounds__(256)
__global__ void k_gemm2(const float* __restrict__ h1, const float* __restrict__ scaleA,
                        const float* __restrict__ shiftA, const float* __restrict__ W,
                        const float* __restrict__ bias, float* __restrict__ out) {
  __shared__ float Als[64][132];
  __shared__ float4 Wls[128 * 32];
  int tid = threadIdx.x;
  int row0 = blockIdx.x * 64;

  const float4* Wf4 = (const float4*)W;
  for (int i = tid; i < 4096; i += 256) Wls[i] = Wf4[i];

  int c4 = tid & 31, rr = tid >> 5;
  float4 sc = ((const float4*)scaleA)[c4];
  float4 sh = ((const float4*)shiftA)[c4];
  for (int it = 0; it < 8; ++it) {
    int r = rr + it * 8;
    int grow = row0 + r;
    float4 a = make_float4(0.f, 0.f, 0.f, 0.f);
    if (grow < Nn) {
      float4 h = ((const float4*)h1)[grow * 32 + c4];
      a.x = fmaxf(fmaf(h.x, sc.x, sh.x), 0.f);
      a.y = fmaxf(fmaf(h.y, sc.y, sh.y), 0.f);
      a.z = fmaxf(fmaf(h.z, sc.z, sh.z), 0.f);
      a.w = fmaxf(fmaf(h.w, sc.w, sh.w), 0.f);
    }
    *(float4*)&Als[r][c4 * 4] = a;
  }
  __syncthreads();

  int tx = tid & 31, ty = tid >> 5;
  float acc[8][4];
#pragma unroll
  for (int i = 0; i < 8; ++i)
#pragma unroll
    for (int j = 0; j < 4; ++j) acc[i][j] = 0.f;

#pragma unroll 4
  for (int k0 = 0; k0 < 128; k0 += 4) {
    float4 b0 = Wls[(k0 + 0) * 32 + tx];
    float4 b1v = Wls[(k0 + 1) * 32 + tx];
    float4 b2v = Wls[(k0 + 2) * 32 + tx];
    float4 b3v = Wls[(k0 + 3) * 32 + tx];
#pragma unroll
    for (int i = 0; i < 8; ++i) {
      float4 av = *(const float4*)&Als[ty * 8 + i][k0];
      acc[i][0] = fmaf(av.x, b0.x, acc[i][0]); acc[i][1] = fmaf(av.x, b0.y, acc[i][1]);
      acc[i][2] = fmaf(av.x, b0.z, acc[i][2]); acc[i][3] = fmaf(av.x, b0.w, acc[i][3]);
      acc[i][0] = fmaf(av.y, b1v.x, acc[i][0]); acc[i][1] = fmaf(av.y, b1v.y, acc[i][1]);
      acc[i][2] = fmaf(av.y, b1v.z, acc[i][2]); acc[i][3] = fmaf(av.y, b1v.w, acc[i][3]);
      acc[i][0] = fmaf(av.z, b2v.x, acc[i][0]); acc[i][1] = fmaf(av.z, b2v.y, acc[i][1]);
      acc[i][2] = fmaf(av.z, b2v.z, acc[i][2]); acc[i][3] = fmaf(av.z, b2v.w, acc[i][3]);
      acc[i][0] = fmaf(av.w, b3v.x, acc[i][0]); acc[i][1] = fmaf(av.w, b3v.y, acc[i][1]);
      acc[i][2] = fmaf(av.w, b3v.z, acc[i][2]); acc[i][3] = fmaf(av.w, b3v.w, acc[i][3]);
    }
  }

  float4 bcol = ((const float4*)bias)[tx];
#pragma unroll
  for (int i = 0; i < 8; ++i) {
    int grow = row0 + ty * 8 + i;
    if (grow < Nn) {
      float4 o;
      o.x = fmaxf(acc[i][0] + bcol.x, 0.f);
      o.y = fmaxf(acc[i][1] + bcol.y, 0.f);
      o.z = fmaxf(acc[i][2] + bcol.z, 0.f);
      o.w = fmaxf(acc[i][3] + bcol.w, 0.f);
      ((float4*)out)[grow * 32 + tx] = o;
    }
  }
}

// ------------------------------ pooling -------------------------------------
__global__ void k_pool(const float* __restrict__ xin, const int* __restrict__ batch,
                       float* __restrict__ pooled, float* __restrict__ gcnt) {
  int wid = threadIdx.x >> 6, lane = threadIdx.x & 63;
  int n = blockIdx.x * 4 + wid;
  if (n >= Nn) return;
  int g = batch[n];
  float2 v = ((const float2*)xin)[n * 64 + lane];
  atomicAdd(&pooled[g * 128 + lane * 2 + 0], v.x);
  atomicAdd(&pooled[g * 128 + lane * 2 + 1], v.y);
  if (lane == 0) atomicAdd(&gcnt[g], 1.0f);
}

__global__ void k_head(const float* __restrict__ pooled, const float* __restrict__ gcnt,
                       const float* __restrict__ Wc, const float* __restrict__ bc,
                       float* __restrict__ out) {
  __shared__ float p[128];
  int g = blockIdx.x, tid = threadIdx.x;
  p[tid] = pooled[g * 128 + tid] / fmaxf(gcnt[g], 1.0f);
  __syncthreads();
  if (tid < Cc) {
    float acc = bc[tid];
    for (int k = 0; k < 128; ++k) acc = fmaf(p[k], Wc[k * Cc + tid], acc);
    out[g * Cc + tid] = acc;
  }
}

// ------------------------------ launcher ------------------------------------
extern "C" void kernel_launch(void* const* d_in, const int* in_sizes, int n_in,
                              void* d_out, int out_size, void* d_ws, size_t ws_size,
                              hipStream_t stream) {
  const float* x    = (const float*)d_in[0];
  const float* ncn  = (const float*)d_in[1];
  const float* ecn  = (const float*)d_in[2];
  const float* W1   = (const float*)d_in[3];
  const float* b1   = (const float*)d_in[4];
  const float* g1   = (const float*)d_in[5];
  const float* be1  = (const float*)d_in[6];
  const float* W2   = (const float*)d_in[7];
  const float* b2   = (const float*)d_in[8];
  const float* Wc   = (const float*)d_in[9];
  const float* bc   = (const float*)d_in[10];
  const int*   ei   = (const int*)d_in[11];
  const int*   batch= (const int*)d_in[12];
  const int* src  = ei;
  const int* dstp = ei + Ee;

  // 3 big buffers (N*128 fp32 each) + small/CSR tail: ~84 MB total
  float* fws = (float*)d_ws;
  float* bufA     = fws;                       // N*128
  float* bufB     = fws +  6400000;            // N*128
  float* h1       = fws + 12800000;            // N*128 (fixed)
  float* colsum   = fws + 19200000;            // 128
  float* colsumsq = colsum + 128;              // 128
  float* scaleA   = colsum + 256;              // 128
  float* shiftA   = colsum + 384;              // 128
  float* pooled   = colsum + 512;              // G*128
  float* gcnt     = pooled + Gg * 128;         // G (pad to 128)
  int*   deg      = (int*)(gcnt + 128);        // N
  int*   offs     = deg + Nn;                  // N+1 (pad)
  int*   cursor   = offs + Nn + 64;            // N
  int*   esrc     = cursor + Nn;               // E
  float* ew       = (float*)(esrc + Ee);       // E

  // build CSR (once per call, reused by all 3 layers)
  hipMemsetAsync(deg, 0, Nn * sizeof(int), stream);
  k_deg<<<1024, 256, 0, stream>>>(dstp, deg);
  k_scan<<<1, 1024, 0, stream>>>(deg, offs, cursor);
  k_fill<<<1024, 256, 0, stream>>>(src, dstp, ecn, cursor, esrc, ew);

  // Buffer schedule (agg is dead after gemm1, so gemm2 may overwrite it):
  //  l0: xin=x    agg=A  h1=C  xout=A
  //  l1: xin=A    agg=B  h1=C  xout=B
  //  l2: xin=B    agg=A  h1=C  xout=A
  const float* xin = x;
  for (int l = 0; l < Ll; ++l) {
    float* aggb = (l & 1) ? bufB : bufA;
    k_agg<<<(Nn + 3) / 4, 256, 0, stream>>>(xin, offs, esrc, ew, aggb);
    hipMemsetAsync(colsum, 0, 256 * sizeof(float), stream);
    k_gemm1<<<(Nn + 63) / 64, 256, 0, stream>>>(aggb, ncn, xin, W1 + l * 128 * 128,
                                                b1 + l * 128, h1, colsum, colsumsq);
    k_bnfin<<<1, 128, 0, stream>>>(colsum, colsumsq, g1 + l * 128, be1 + l * 128,
                                   scaleA, shiftA);
    k_gemm2<<<(Nn + 63) / 64, 256, 0, stream>>>(h1, scaleA, shiftA, W2 + l * 128 * 128,
                                                b2 + l * 128, aggb);
    xin = aggb;
  }

  hipMemsetAsync(pooled, 0, (Gg * 128 + 128) * sizeof(float), stream);
  k_pool<<<(Nn + 3) / 4, 256, 0, stream>>>(xin, batch, pooled, gcnt);
  k_head<<<Gg, 128, 0, stream>>>(pooled, gcnt, Wc, bc, (float*)d_out);
}

// Round 3
// 1199.574 us; speedup vs baseline: 2.4068x; 2.4068x over previous
//
#include <hip/hip_runtime.h>

#define Nn 50000
#define Ee 800000
#define HD 128        // D == H == 128
#define Ll 3
#define Gg 128
#define Cc 10
#define BN_EPS 1e-5f
#define NBLK1 782     // ceil(Nn/64) — gemm row-tiles / BN partial rows

// ----------------------------- CSR build ------------------------------------
__global__ void k_deg(const int* __restrict__ dst, int* __restrict__ deg) {
  int i = blockIdx.x * blockDim.x + threadIdx.x;
  int stride = gridDim.x * blockDim.x;
  for (int e = i; e < Ee; e += stride) atomicAdd(&deg[dst[e]], 1);
}

// single-block exclusive scan over deg[Nn] -> offs[Nn+1], copy to cursor
__global__ void k_scan(const int* __restrict__ deg, int* __restrict__ offs,
                       int* __restrict__ cursor) {
  __shared__ int b0[1024], b1[1024];
  __shared__ int carry;
  int tid = threadIdx.x;
  if (tid == 0) carry = 0;
  __syncthreads();
  const int ntile = (Nn + 1023) >> 10;
  for (int t = 0; t < ntile; ++t) {
    int i = (t << 10) + tid;
    int v = (i < Nn) ? deg[i] : 0;
    int* cur = b0; int* nxt = b1;
    cur[tid] = v;
    __syncthreads();
    for (int off = 1; off < 1024; off <<= 1) {
      int s = cur[tid] + ((tid >= off) ? cur[tid - off] : 0);
      nxt[tid] = s;
      __syncthreads();
      int* tmp = cur; cur = nxt; nxt = tmp;
    }
    int incl = cur[tid];
    int tot  = cur[1023];
    int excl = incl - v + carry;
    if (i < Nn) { offs[i] = excl; cursor[i] = excl; }
    __syncthreads();
    if (tid == 0) carry += tot;
    __syncthreads();
  }
  if (tid == 0) offs[Nn] = carry;   // == Ee
}

__global__ void k_fill(const int* __restrict__ src, const int* __restrict__ dst,
                       const float* __restrict__ ec, int* __restrict__ cursor,
                       int* __restrict__ esrc, float* __restrict__ ew) {
  int i = blockIdx.x * blockDim.x + threadIdx.x;
  int stride = gridDim.x * blockDim.x;
  for (int e = i; e < Ee; e += stride) {
    int d = dst[e];
    int p = atomicAdd(&cursor[d], 1);
    esrc[p] = src[e];
    ew[p]   = ec[e];
  }
}

// -------------------- aggregation: gather (one wave per node) ---------------
__global__ void k_agg(const float* __restrict__ xin, const int* __restrict__ offs,
                      const int* __restrict__ esrc, const float* __restrict__ ew,
                      float* __restrict__ agg) {
  int wid = threadIdx.x >> 6, lane = threadIdx.x & 63;
  int n = blockIdx.x * 4 + wid;
  if (n >= Nn) return;
  int beg = offs[n], end = offs[n + 1];
  const float2* x2 = (const float2*)xin;
  float2 acc = make_float2(0.f, 0.f);
  for (int j = beg; j < end; ++j) {
    int s = esrc[j];
    float w = ew[j];
    float2 v = x2[s * 64 + lane];
    acc.x = fmaf(v.x, w, acc.x);
    acc.y = fmaf(v.y, w, acc.y);
  }
  ((float2*)agg)[n * 64 + lane] = acc;
}

// -------------------- GEMM1: h1 = (agg*nc + x) @ W1 + b1, + BN partials -----
// 64-row tile, 256 threads, thread computes 8 rows x 4 cols. K=128 fully in LDS.
// BN stats: per-block LDS reduction -> ONE non-atomic 256-float partial row
// per block (contended-atomic fix: 1.6M global atomics -> 0).
__launch_bounds__(256)
__global__ void k_gemm1(const float* __restrict__ agg, const float* __restrict__ nc,
                        const float* __restrict__ xin, const float* __restrict__ W,
                        const float* __restrict__ bias, float* __restrict__ out,
                        float* __restrict__ partial) {
  __shared__ float Als[64][132];       // row-major, padded stride
  __shared__ float4 Wls[128 * 32];     // [k][col4]
  int tid = threadIdx.x;
  int row0 = blockIdx.x * 64;

  const float4* Wf4 = (const float4*)W;
  for (int i = tid; i < 4096; i += 256) Wls[i] = Wf4[i];

  int c4 = tid & 31, rr = tid >> 5;
  for (int it = 0; it < 8; ++it) {
    int r = rr + it * 8;
    int grow = row0 + r;
    float4 a = make_float4(0.f, 0.f, 0.f, 0.f);
    if (grow < Nn) {
      float4 ag = ((const float4*)agg)[grow * 32 + c4];
      float4 xv = ((const float4*)xin)[grow * 32 + c4];
      float nv = nc[grow];
      a.x = fmaf(ag.x, nv, xv.x); a.y = fmaf(ag.y, nv, xv.y);
      a.z = fmaf(ag.z, nv, xv.z); a.w = fmaf(ag.w, nv, xv.w);
    }
    *(float4*)&Als[r][c4 * 4] = a;
  }
  __syncthreads();

  int tx = tid & 31, ty = tid >> 5;
  float acc[8][4];
#pragma unroll
  for (int i = 0; i < 8; ++i)
#pragma unroll
    for (int j = 0; j < 4; ++j) acc[i][j] = 0.f;

#pragma unroll 4
  for (int k0 = 0; k0 < 128; k0 += 4) {
    float4 b0 = Wls[(k0 + 0) * 32 + tx];
    float4 b1v = Wls[(k0 + 1) * 32 + tx];
    float4 b2v = Wls[(k0 + 2) * 32 + tx];
    float4 b3v = Wls[(k0 + 3) * 32 + tx];
#pragma unroll
    for (int i = 0; i < 8; ++i) {
      float4 av = *(const float4*)&Als[ty * 8 + i][k0];
      acc[i][0] = fmaf(av.x, b0.x, acc[i][0]); acc[i][1] = fmaf(av.x, b0.y, acc[i][1]);
      acc[i][2] = fmaf(av.x, b0.z, acc[i][2]); acc[i][3] = fmaf(av.x, b0.w, acc[i][3]);
      acc[i][0] = fmaf(av.y, b1v.x, acc[i][0]); acc[i][1] = fmaf(av.y, b1v.y, acc[i][1]);
      acc[i][2] = fmaf(av.y, b1v.z, acc[i][2]); acc[i][3] = fmaf(av.y, b1v.w, acc[i][3]);
      acc[i][0] = fmaf(av.z, b2v.x, acc[i][0]); acc[i][1] = fmaf(av.z, b2v.y, acc[i][1]);
      acc[i][2] = fmaf(av.z, b2v.z, acc[i][2]); acc[i][3] = fmaf(av.z, b2v.w, acc[i][3]);
      acc[i][0] = fmaf(av.w, b3v.x, acc[i][0]); acc[i][1] = fmaf(av.w, b3v.y, acc[i][1]);
      acc[i][2] = fmaf(av.w, b3v.z, acc[i][2]); acc[i][3] = fmaf(av.w, b3v.w, acc[i][3]);
    }
  }

  float4 bcol = ((const float4*)bias)[tx];
  float s0 = 0, s1 = 0, s2 = 0, s3 = 0, q0 = 0, q1 = 0, q2 = 0, q3 = 0;
#pragma unroll
  for (int i = 0; i < 8; ++i) {
    int grow = row0 + ty * 8 + i;
    if (grow < Nn) {
      float4 o;
      o.x = acc[i][0] + bcol.x; o.y = acc[i][1] + bcol.y;
      o.z = acc[i][2] + bcol.z; o.w = acc[i][3] + bcol.w;
      ((float4*)out)[grow * 32 + tx] = o;
      s0 += o.x; s1 += o.y; s2 += o.z; s3 += o.w;
      q0 += o.x * o.x; q1 += o.y * o.y; q2 += o.z * o.z; q3 += o.w * o.w;
    }
  }

  // block-level reduction over ty (8 threads per column group) in LDS
  __syncthreads();                       // done reading Als
  float* red = (float*)Als;              // reuse: 256 threads x 8 floats
  red[tid * 8 + 0] = s0; red[tid * 8 + 1] = s1;
  red[tid * 8 + 2] = s2; red[tid * 8 + 3] = s3;
  red[tid * 8 + 4] = q0; red[tid * 8 + 5] = q1;
  red[tid * 8 + 6] = q2; red[tid * 8 + 7] = q3;
  __syncthreads();
  if (ty == 0) {
    float v[8];
#pragma unroll
    for (int j = 0; j < 8; ++j) v[j] = 0.f;
    for (int t = 0; t < 8; ++t) {
      int id = t * 32 + tx;
#pragma unroll
      for (int j = 0; j < 8; ++j) v[j] += red[id * 8 + j];
    }
    float* ps = partial + blockIdx.x * 256;
    ps[tx * 4 + 0] = v[0]; ps[tx * 4 + 1] = v[1];
    ps[tx * 4 + 2] = v[2]; ps[tx * 4 + 3] = v[3];
    ps[128 + tx * 4 + 0] = v[4]; ps[128 + tx * 4 + 1] = v[5];
    ps[128 + tx * 4 + 2] = v[6]; ps[128 + tx * 4 + 3] = v[7];
  }
}

// reduce per-block partials; scaleA = rsqrt(var+eps)*g1 ; shiftA = be1 - mu*scaleA
__global__ void k_bnfin(const float* __restrict__ partial,
                        const float* __restrict__ g1, const float* __restrict__ be1,
                        float* __restrict__ scaleA, float* __restrict__ shiftA) {
  int f = threadIdx.x;   // 128 threads
  float s = 0.f, q = 0.f;
  for (int b = 0; b < NBLK1; ++b) {
    s += partial[b * 256 + f];
    q += partial[b * 256 + 128 + f];
  }
  const float inv = 1.0f / (float)Nn;
  float mu = s * inv;
  float var = fmaxf(q * inv - mu * mu, 0.f);
  float rs = rsqrtf(var + BN_EPS);
  float sc = rs * g1[f];
  scaleA[f] = sc;
  shiftA[f] = be1[f] - mu * sc;
}

// -------- GEMM2: xout = relu( relu(h1*scaleA+shiftA) @ W2 + b2 ) ------------
__launch_bounds__(256)
__global__ void k_gemm2(const float* __restrict__ h1, const float* __restrict__ scaleA,
                        const float* __restrict__ shiftA, const float* __restrict__ W,
                        const float* __restrict__ bias, float* __restrict__ out) {
  __shared__ float Als[64][132];
  __shared__ float4 Wls[128 * 32];
  int tid = threadIdx.x;
  int row0 = blockIdx.x * 64;

  const float4* Wf4 = (const float4*)W;
  for (int i = tid; i < 4096; i += 256) Wls[i] = Wf4[i];

  int c4 = tid & 31, rr = tid >> 5;
  float4 sc = ((const float4*)scaleA)[c4];
  float4 sh = ((const float4*)shiftA)[c4];
  for (int it = 0; it < 8; ++it) {
    int r = rr + it * 8;
    int grow = row0 + r;
    float4 a = make_float4(0.f, 0.f, 0.f, 0.f);
    if (grow < Nn) {
      float4 h = ((const float4*)h1)[grow * 32 + c4];
      a.x = fmaxf(fmaf(h.x, sc.x, sh.x), 0.f);
      a.y = fmaxf(fmaf(h.y, sc.y, sh.y), 0.f);
      a.z = fmaxf(fmaf(h.z, sc.z, sh.z), 0.f);
      a.w = fmaxf(fmaf(h.w, sc.w, sh.w), 0.f);
    }
    *(float4*)&Als[r][c4 * 4] = a;
  }
  __syncthreads();

  int tx = tid & 31, ty = tid >> 5;
  float acc[8][4];
#pragma unroll
  for (int i = 0; i < 8; ++i)
#pragma unroll
    for (int j = 0; j < 4; ++j) acc[i][j] = 0.f;

#pragma unroll 4
  for (int k0 = 0; k0 < 128; k0 += 4) {
    float4 b0 = Wls[(k0 + 0) * 32 + tx];
    float4 b1v = Wls[(k0 + 1) * 32 + tx];
    float4 b2v = Wls[(k0 + 2) * 32 + tx];
    float4 b3v = Wls[(k0 + 3) * 32 + tx];
#pragma unroll
    for (int i = 0; i < 8; ++i) {
      float4 av = *(const float4*)&Als[ty * 8 + i][k0];
      acc[i][0] = fmaf(av.x, b0.x, acc[i][0]); acc[i][1] = fmaf(av.x, b0.y, acc[i][1]);
      acc[i][2] = fmaf(av.x, b0.z, acc[i][2]); acc[i][3] = fmaf(av.x, b0.w, acc[i][3]);
      acc[i][0] = fmaf(av.y, b1v.x, acc[i][0]); acc[i][1] = fmaf(av.y, b1v.y, acc[i][1]);
      acc[i][2] = fmaf(av.y, b1v.z, acc[i][2]); acc[i][3] = fmaf(av.y, b1v.w, acc[i][3]);
      acc[i][0] = fmaf(av.z, b2v.x, acc[i][0]); acc[i][1] = fmaf(av.z, b2v.y, acc[i][1]);
      acc[i][2] = fmaf(av.z, b2v.z, acc[i][2]); acc[i][3] = fmaf(av.z, b2v.w, acc[i][3]);
      acc[i][0] = fmaf(av.w, b3v.x, acc[i][0]); acc[i][1] = fmaf(av.w, b3v.y, acc[i][1]);
      acc[i][2] = fmaf(av.w, b3v.z, acc[i][2]); acc[i][3] = fmaf(av.w, b3v.w, acc[i][3]);
    }
  }

  float4 bcol = ((const float4*)bias)[tx];
#pragma unroll
  for (int i = 0; i < 8; ++i) {
    int grow = row0 + ty * 8 + i;
    if (grow < Nn) {
      float4 o;
      o.x = fmaxf(acc[i][0] + bcol.x, 0.f);
      o.y = fmaxf(acc[i][1] + bcol.y, 0.f);
      o.z = fmaxf(acc[i][2] + bcol.z, 0.f);
      o.w = fmaxf(acc[i][3] + bcol.w, 0.f);
      ((float4*)out)[grow * 32 + tx] = o;
    }
  }
}

// ------------------------------ pooling -------------------------------------
// batch is SORTED: one wave per 64 consecutive nodes, run-length accumulate in
// registers, flush to global atomics only on group change (~50x fewer atomics).
#define PCH 64
__global__ void k_pool(const float* __restrict__ xin, const int* __restrict__ batch,
                       float* __restrict__ pooled, float* __restrict__ gcnt) {
  int wid = threadIdx.x >> 6, lane = threadIdx.x & 63;
  int w = blockIdx.x * 4 + wid;
  int n0 = w * PCH;
  if (n0 >= Nn) return;
  int n1 = (n0 + PCH < Nn) ? n0 + PCH : Nn;
  const float2* x2 = (const float2*)xin;
  float2 acc = make_float2(0.f, 0.f);
  int cur = batch[n0];
  int cnt = 0;
  for (int n = n0; n < n1; ++n) {
    int g = batch[n];                    // wave-uniform
    if (g != cur) {
      atomicAdd(&pooled[cur * 128 + lane * 2 + 0], acc.x);
      atomicAdd(&pooled[cur * 128 + lane * 2 + 1], acc.y);
      if (lane == 0) atomicAdd(&gcnt[cur], (float)cnt);
      acc = make_float2(0.f, 0.f); cnt = 0; cur = g;
    }
    float2 v = x2[n * 64 + lane];
    acc.x += v.x; acc.y += v.y; ++cnt;
  }
  atomicAdd(&pooled[cur * 128 + lane * 2 + 0], acc.x);
  atomicAdd(&pooled[cur * 128 + lane * 2 + 1], acc.y);
  if (lane == 0) atomicAdd(&gcnt[cur], (float)cnt);
}

__global__ void k_head(const float* __restrict__ pooled, const float* __restrict__ gcnt,
                       const float* __restrict__ Wc, const float* __restrict__ bc,
                       float* __restrict__ out) {
  __shared__ float p[128];
  int g = blockIdx.x, tid = threadIdx.x;
  p[tid] = pooled[g * 128 + tid] / fmaxf(gcnt[g], 1.0f);
  __syncthreads();
  if (tid < Cc) {
    float acc = bc[tid];
    for (int k = 0; k < 128; ++k) acc = fmaf(p[k], Wc[k * Cc + tid], acc);
    out[g * Cc + tid] = acc;
  }
}

// ------------------------------ launcher ------------------------------------
extern "C" void kernel_launch(void* const* d_in, const int* in_sizes, int n_in,
                              void* d_out, int out_size, void* d_ws, size_t ws_size,
                              hipStream_t stream) {
  const float* x    = (const float*)d_in[0];
  const float* ncn  = (const float*)d_in[1];
  const float* ecn  = (const float*)d_in[2];
  const float* W1   = (const float*)d_in[3];
  const float* b1   = (const float*)d_in[4];
  const float* g1   = (const float*)d_in[5];
  const float* be1  = (const float*)d_in[6];
  const float* W2   = (const float*)d_in[7];
  const float* b2   = (const float*)d_in[8];
  const float* Wc   = (const float*)d_in[9];
  const float* bc   = (const float*)d_in[10];
  const int*   ei   = (const int*)d_in[11];
  const int*   batch= (const int*)d_in[12];
  const int* src  = ei;
  const int* dstp = ei + Ee;

  // 3 big buffers (N*128 fp32 each) + partials + small/CSR tail: ~85 MB total
  float* fws = (float*)d_ws;
  float* bufA     = fws;                       // N*128
  float* bufB     = fws +  6400000;            // N*128
  float* h1       = fws + 12800000;            // N*128 (fixed)
  float* partial  = fws + 19200000;            // NBLK1*256 (800 KB)
  float* scaleA   = partial + NBLK1 * 256;     // 128
  float* shiftA   = scaleA + 128;              // 128
  float* pooled   = shiftA + 128;              // G*128
  float* gcnt     = pooled + Gg * 128;         // G (pad to 128)
  int*   deg      = (int*)(gcnt + 128);        // N
  int*   offs     = deg + Nn;                  // N+1 (pad)
  int*   cursor   = offs + Nn + 64;            // N
  int*   esrc     = cursor + Nn;               // E
  float* ew       = (float*)(esrc + Ee);       // E

  // build CSR (once per call, reused by all 3 layers)
  hipMemsetAsync(deg, 0, Nn * sizeof(int), stream);
  k_deg<<<1024, 256, 0, stream>>>(dstp, deg);
  k_scan<<<1, 1024, 0, stream>>>(deg, offs, cursor);
  k_fill<<<1024, 256, 0, stream>>>(src, dstp, ecn, cursor, esrc, ew);

  // Buffer schedule (agg is dead after gemm1, so gemm2 may overwrite it):
  //  l0: xin=x    agg=A  h1=C  xout=A
  //  l1: xin=A    agg=B  h1=C  xout=B
  //  l2: xin=B    agg=A  h1=C  xout=A
  const float* xin = x;
  for (int l = 0; l < Ll; ++l) {
    float* aggb = (l & 1) ? bufB : bufA;
    k_agg<<<(Nn + 3) / 4, 256, 0, stream>>>(xin, offs, esrc, ew, aggb);
    k_gemm1<<<NBLK1, 256, 0, stream>>>(aggb, ncn, xin, W1 + l * 128 * 128,
                                       b1 + l * 128, h1, partial);
    k_bnfin<<<1, 128, 0, stream>>>(partial, g1 + l * 128, be1 + l * 128,
                                   scaleA, shiftA);
    k_gemm2<<<NBLK1, 256, 0, stream>>>(h1, scaleA, shiftA, W2 + l * 128 * 128,
                                       b2 + l * 128, aggb);
    xin = aggb;
  }

  hipMemsetAsync(pooled, 0, (Gg * 128 + 128) * sizeof(float), stream);
  k_pool<<<(Nn + PCH * 4 - 1) / (PCH * 4), 256, 0, stream>>>(xin, batch, pooled, gcnt);
  k_head<<<Gg, 128, 0, stream>>>(pooled, gcnt, Wc, bc, (float*)d_out);
}

// Round 4
// 846.191 us; speedup vs baseline: 3.4119x; 1.4176x over previous
//
#include <hip/hip_runtime.h>

#define Nn 50000
#define Ee 800000
#define HD 128        // D == H == 128
#define Ll 3
#define Gg 128
#define Cc 10
#define BN_EPS 1e-5f
#define NBLK1 782     // ceil(Nn/64) — gemm row-tiles / BN partial rows
#define PPAD 800      // padded partial stride (feature-major layout)

// ----------------------------- CSR build ------------------------------------
__global__ void k_deg(const int* __restrict__ dst, int* __restrict__ deg) {
  int i = blockIdx.x * blockDim.x + threadIdx.x;
  int stride = gridDim.x * blockDim.x;
  for (int e = i; e < Ee; e += stride) atomicAdd(&deg[dst[e]], 1);
}

// single-block exclusive scan over deg[Nn] -> offs[Nn+1], copy to cursor
__global__ void k_scan(const int* __restrict__ deg, int* __restrict__ offs,
                       int* __restrict__ cursor) {
  __shared__ int b0[1024], b1[1024];
  __shared__ int carry;
  int tid = threadIdx.x;
  if (tid == 0) carry = 0;
  __syncthreads();
  const int ntile = (Nn + 1023) >> 10;
  for (int t = 0; t < ntile; ++t) {
    int i = (t << 10) + tid;
    int v = (i < Nn) ? deg[i] : 0;
    int* cur = b0; int* nxt = b1;
    cur[tid] = v;
    __syncthreads();
    for (int off = 1; off < 1024; off <<= 1) {
      int s = cur[tid] + ((tid >= off) ? cur[tid - off] : 0);
      nxt[tid] = s;
      __syncthreads();
      int* tmp = cur; cur = nxt; nxt = tmp;
    }
    int incl = cur[tid];
    int tot  = cur[1023];
    int excl = incl - v + carry;
    if (i < Nn) { offs[i] = excl; cursor[i] = excl; }
    __syncthreads();
    if (tid == 0) carry += tot;
    __syncthreads();
  }
  if (tid == 0) offs[Nn] = carry;   // == Ee
}

__global__ void k_fill(const int* __restrict__ src, const int* __restrict__ dst,
                       const float* __restrict__ ec, int* __restrict__ cursor,
                       int* __restrict__ esrc, float* __restrict__ ew) {
  int i = blockIdx.x * blockDim.x + threadIdx.x;
  int stride = gridDim.x * blockDim.x;
  for (int e = i; e < Ee; e += stride) {
    int d = dst[e];
    int p = atomicAdd(&cursor[d], 1);
    esrc[p] = src[e];
    ew[p]   = ec[e];
  }
}

// -------------------- aggregation: gather (one wave per node) ---------------
// 2-edge unroll, independent accumulators: two row-loads in flight per iter.
__global__ void k_agg(const float* __restrict__ xin, const int* __restrict__ offs,
                      const int* __restrict__ esrc, const float* __restrict__ ew,
                      float* __restrict__ agg) {
  int wid = threadIdx.x >> 6, lane = threadIdx.x & 63;
  int n = blockIdx.x * 4 + wid;
  if (n >= Nn) return;
  int beg = offs[n], end = offs[n + 1];
  const float2* x2 = (const float2*)xin;
  float2 acc0 = make_float2(0.f, 0.f);
  float2 acc1 = make_float2(0.f, 0.f);
  int j = beg;
  for (; j + 1 < end; j += 2) {
    int s0 = esrc[j], s1 = esrc[j + 1];
    float w0 = ew[j], w1 = ew[j + 1];
    float2 v0 = x2[s0 * 64 + lane];
    float2 v1 = x2[s1 * 64 + lane];
    acc0.x = fmaf(v0.x, w0, acc0.x); acc0.y = fmaf(v0.y, w0, acc0.y);
    acc1.x = fmaf(v1.x, w1, acc1.x); acc1.y = fmaf(v1.y, w1, acc1.y);
  }
  if (j < end) {
    int s0 = esrc[j];
    float w0 = ew[j];
    float2 v0 = x2[s0 * 64 + lane];
    acc0.x = fmaf(v0.x, w0, acc0.x); acc0.y = fmaf(v0.y, w0, acc0.y);
  }
  acc0.x += acc1.x; acc0.y += acc1.y;
  ((float2*)agg)[n * 64 + lane] = acc0;
}

// -------------------- GEMM1: h1 = (agg*nc + x) @ W1 + b1, + BN partials -----
// 64-row tile, 256 threads, thread computes 8 rows x 4 cols. K=128 fully in LDS.
// BN partials written FEATURE-MAJOR (partial[f*PPAD + blk]) so k_bnfin reads
// are coalesced per feature.
__launch_bounds__(256)
__global__ void k_gemm1(const float* __restrict__ agg, const float* __restrict__ nc,
                        const float* __restrict__ xin, const float* __restrict__ W,
                        const float* __restrict__ bias, float* __restrict__ out,
                        float* __restrict__ partial) {
  __shared__ float Als[64][132];       // row-major, padded stride
  __shared__ float4 Wls[128 * 32];     // [k][col4]
  int tid = threadIdx.x;
  int row0 = blockIdx.x * 64;

  const float4* Wf4 = (const float4*)W;
  for (int i = tid; i < 4096; i += 256) Wls[i] = Wf4[i];

  int c4 = tid & 31, rr = tid >> 5;
  for (int it = 0; it < 8; ++it) {
    int r = rr + it * 8;
    int grow = row0 + r;
    float4 a = make_float4(0.f, 0.f, 0.f, 0.f);
    if (grow < Nn) {
      float4 ag = ((const float4*)agg)[grow * 32 + c4];
      float4 xv = ((const float4*)xin)[grow * 32 + c4];
      float nv = nc[grow];
      a.x = fmaf(ag.x, nv, xv.x); a.y = fmaf(ag.y, nv, xv.y);
      a.z = fmaf(ag.z, nv, xv.z); a.w = fmaf(ag.w, nv, xv.w);
    }
    *(float4*)&Als[r][c4 * 4] = a;
  }
  __syncthreads();

  int tx = tid & 31, ty = tid >> 5;
  float acc[8][4];
#pragma unroll
  for (int i = 0; i < 8; ++i)
#pragma unroll
    for (int j = 0; j < 4; ++j) acc[i][j] = 0.f;

#pragma unroll 4
  for (int k0 = 0; k0 < 128; k0 += 4) {
    float4 b0 = Wls[(k0 + 0) * 32 + tx];
    float4 b1v = Wls[(k0 + 1) * 32 + tx];
    float4 b2v = Wls[(k0 + 2) * 32 + tx];
    float4 b3v = Wls[(k0 + 3) * 32 + tx];
#pragma unroll
    for (int i = 0; i < 8; ++i) {
      float4 av = *(const float4*)&Als[ty * 8 + i][k0];
      acc[i][0] = fmaf(av.x, b0.x, acc[i][0]); acc[i][1] = fmaf(av.x, b0.y, acc[i][1]);
      acc[i][2] = fmaf(av.x, b0.z, acc[i][2]); acc[i][3] = fmaf(av.x, b0.w, acc[i][3]);
      acc[i][0] = fmaf(av.y, b1v.x, acc[i][0]); acc[i][1] = fmaf(av.y, b1v.y, acc[i][1]);
      acc[i][2] = fmaf(av.y, b1v.z, acc[i][2]); acc[i][3] = fmaf(av.y, b1v.w, acc[i][3]);
      acc[i][0] = fmaf(av.z, b2v.x, acc[i][0]); acc[i][1] = fmaf(av.z, b2v.y, acc[i][1]);
      acc[i][2] = fmaf(av.z, b2v.z, acc[i][2]); acc[i][3] = fmaf(av.z, b2v.w, acc[i][3]);
      acc[i][0] = fmaf(av.w, b3v.x, acc[i][0]); acc[i][1] = fmaf(av.w, b3v.y, acc[i][1]);
      acc[i][2] = fmaf(av.w, b3v.z, acc[i][2]); acc[i][3] = fmaf(av.w, b3v.w, acc[i][3]);
    }
  }

  float4 bcol = ((const float4*)bias)[tx];
  float s0 = 0, s1 = 0, s2 = 0, s3 = 0, q0 = 0, q1 = 0, q2 = 0, q3 = 0;
#pragma unroll
  for (int i = 0; i < 8; ++i) {
    int grow = row0 + ty * 8 + i;
    if (grow < Nn) {
      float4 o;
      o.x = acc[i][0] + bcol.x; o.y = acc[i][1] + bcol.y;
      o.z = acc[i][2] + bcol.z; o.w = acc[i][3] + bcol.w;
      ((float4*)out)[grow * 32 + tx] = o;
      s0 += o.x; s1 += o.y; s2 += o.z; s3 += o.w;
      q0 += o.x * o.x; q1 += o.y * o.y; q2 += o.z * o.z; q3 += o.w * o.w;
    }
  }

  // block-level reduction over ty (8 threads per column group) in LDS
  __syncthreads();                       // done reading Als
  float* red = (float*)Als;              // reuse: 256 threads x 8 floats
  red[tid * 8 + 0] = s0; red[tid * 8 + 1] = s1;
  red[tid * 8 + 2] = s2; red[tid * 8 + 3] = s3;
  red[tid * 8 + 4] = q0; red[tid * 8 + 5] = q1;
  red[tid * 8 + 6] = q2; red[tid * 8 + 7] = q3;
  __syncthreads();
  if (ty == 0) {
    float v[8];
#pragma unroll
    for (int j = 0; j < 8; ++j) v[j] = 0.f;
    for (int t = 0; t < 8; ++t) {
      int id = t * 32 + tx;
#pragma unroll
      for (int j = 0; j < 8; ++j) v[j] += red[id * 8 + j];
    }
    int blk = blockIdx.x;
#pragma unroll
    for (int j = 0; j < 4; ++j) {
      partial[(tx * 4 + j) * PPAD + blk]         = v[j];      // sums
      partial[(128 + tx * 4 + j) * PPAD + blk]   = v[4 + j];  // sumsq
    }
  }
}

// parallel partial reduce: one block per feature, coalesced strided reads.
__global__ void k_bnfin(const float* __restrict__ partial,
                        const float* __restrict__ g1, const float* __restrict__ be1,
                        float* __restrict__ scaleA, float* __restrict__ shiftA) {
  __shared__ float ss[256], qq[256];
  int f = blockIdx.x, t = threadIdx.x;
  float s = 0.f, q = 0.f;
  for (int b = t; b < NBLK1; b += 256) {
    s += partial[f * PPAD + b];
    q += partial[(128 + f) * PPAD + b];
  }
  ss[t] = s; qq[t] = q;
  __syncthreads();
  for (int off = 128; off > 0; off >>= 1) {
    if (t < off) { ss[t] += ss[t + off]; qq[t] += qq[t + off]; }
    __syncthreads();
  }
  if (t == 0) {
    const float inv = 1.0f / (float)Nn;
    float mu = ss[0] * inv;
    float var = fmaxf(qq[0] * inv - mu * mu, 0.f);
    float rs = rsqrtf(var + BN_EPS);
    float sc = rs * g1[f];
    scaleA[f] = sc;
    shiftA[f] = be1[f] - mu * sc;
  }
}

// -------- GEMM2: xout = relu( relu(h1*scaleA+shiftA) @ W2 + b2 ) ------------
__launch_bounds__(256)
__global__ void k_gemm2(const float* __restrict__ h1, const float* __restrict__ scaleA,
                        const float* __restrict__ shiftA, const float* __restrict__ W,
                        const float* __restrict__ bias, float* __restrict__ out) {
  __shared__ float Als[64][132];
  __shared__ float4 Wls[128 * 32];
  int tid = threadIdx.x;
  int row0 = blockIdx.x * 64;

  const float4* Wf4 = (const float4*)W;
  for (int i = tid; i < 4096; i += 256) Wls[i] = Wf4[i];

  int c4 = tid & 31, rr = tid >> 5;
  float4 sc = ((const float4*)scaleA)[c4];
  float4 sh = ((const float4*)shiftA)[c4];
  for (int it = 0; it < 8; ++it) {
    int r = rr + it * 8;
    int grow = row0 + r;
    float4 a = make_float4(0.f, 0.f, 0.f, 0.f);
    if (grow < Nn) {
      float4 h = ((const float4*)h1)[grow * 32 + c4];
      a.x = fmaxf(fmaf(h.x, sc.x, sh.x), 0.f);
      a.y = fmaxf(fmaf(h.y, sc.y, sh.y), 0.f);
      a.z = fmaxf(fmaf(h.z, sc.z, sh.z), 0.f);
      a.w = fmaxf(fmaf(h.w, sc.w, sh.w), 0.f);
    }
    *(float4*)&Als[r][c4 * 4] = a;
  }
  __syncthreads();

  int tx = tid & 31, ty = tid >> 5;
  float acc[8][4];
#pragma unroll
  for (int i = 0; i < 8; ++i)
#pragma unroll
    for (int j = 0; j < 4; ++j) acc[i][j] = 0.f;

#pragma unroll 4
  for (int k0 = 0; k0 < 128; k0 += 4) {
    float4 b0 = Wls[(k0 + 0) * 32 + tx];
    float4 b1v = Wls[(k0 + 1) * 32 + tx];
    float4 b2v = Wls[(k0 + 2) * 32 + tx];
    float4 b3v = Wls[(k0 + 3) * 32 + tx];
#pragma unroll
    for (int i = 0; i < 8; ++i) {
      float4 av = *(const float4*)&Als[ty * 8 + i][k0];
      acc[i][0] = fmaf(av.x, b0.x, acc[i][0]); acc[i][1] = fmaf(av.x, b0.y, acc[i][1]);
      acc[i][2] = fmaf(av.x, b0.z, acc[i][2]); acc[i][3] = fmaf(av.x, b0.w, acc[i][3]);
      acc[i][0] = fmaf(av.y, b1v.x, acc[i][0]); acc[i][1] = fmaf(av.y, b1v.y, acc[i][1]);
      acc[i][2] = fmaf(av.y, b1v.z, acc[i][2]); acc[i][3] = fmaf(av.y, b1v.w, acc[i][3]);
      acc[i][0] = fmaf(av.z, b2v.x, acc[i][0]); acc[i][1] = fmaf(av.z, b2v.y, acc[i][1]);
      acc[i][2] = fmaf(av.z, b2v.z, acc[i][2]); acc[i][3] = fmaf(av.z, b2v.w, acc[i][3]);
      acc[i][0] = fmaf(av.w, b3v.x, acc[i][0]); acc[i][1] = fmaf(av.w, b3v.y, acc[i][1]);
      acc[i][2] = fmaf(av.w, b3v.z, acc[i][2]); acc[i][3] = fmaf(av.w, b3v.w, acc[i][3]);
    }
  }

  float4 bcol = ((const float4*)bias)[tx];
#pragma unroll
  for (int i = 0; i < 8; ++i) {
    int grow = row0 + ty * 8 + i;
    if (grow < Nn) {
      float4 o;
      o.x = fmaxf(acc[i][0] + bcol.x, 0.f);
      o.y = fmaxf(acc[i][1] + bcol.y, 0.f);
      o.z = fmaxf(acc[i][2] + bcol.z, 0.f);
      o.w = fmaxf(acc[i][3] + bcol.w, 0.f);
      ((float4*)out)[grow * 32 + tx] = o;
    }
  }
}

// ------------------------------ pooling -------------------------------------
// batch is SORTED: one wave per 64 consecutive nodes, run-length accumulate in
// registers, flush to global atomics only on group change (~50x fewer atomics).
#define PCH 64
__global__ void k_pool(const float* __restrict__ xin, const int* __restrict__ batch,
                       float* __restrict__ pooled, float* __restrict__ gcnt) {
  int wid = threadIdx.x >> 6, lane = threadIdx.x & 63;
  int w = blockIdx.x * 4 + wid;
  int n0 = w * PCH;
  if (n0 >= Nn) return;
  int n1 = (n0 + PCH < Nn) ? n0 + PCH : Nn;
  const float2* x2 = (const float2*)xin;
  float2 acc = make_float2(0.f, 0.f);
  int cur = batch[n0];
  int cnt = 0;
  for (int n = n0; n < n1; ++n) {
    int g = batch[n];                    // wave-uniform
    if (g != cur) {
      atomicAdd(&pooled[cur * 128 + lane * 2 + 0], acc.x);
      atomicAdd(&pooled[cur * 128 + lane * 2 + 1], acc.y);
      if (lane == 0) atomicAdd(&gcnt[cur], (float)cnt);
      acc = make_float2(0.f, 0.f); cnt = 0; cur = g;
    }
    float2 v = x2[n * 64 + lane];
    acc.x += v.x; acc.y += v.y; ++cnt;
  }
  atomicAdd(&pooled[cur * 128 + lane * 2 + 0], acc.x);
  atomicAdd(&pooled[cur * 128 + lane * 2 + 1], acc.y);
  if (lane == 0) atomicAdd(&gcnt[cur], (float)cnt);
}

__global__ void k_head(const float* __restrict__ pooled, const float* __restrict__ gcnt,
                       const float* __restrict__ Wc, const float* __restrict__ bc,
                       float* __restrict__ out) {
  __shared__ float p[128];
  int g = blockIdx.x, tid = threadIdx.x;
  p[tid] = pooled[g * 128 + tid] / fmaxf(gcnt[g], 1.0f);
  __syncthreads();
  if (tid < Cc) {
    float acc = bc[tid];
    for (int k = 0; k < 128; ++k) acc = fmaf(p[k], Wc[k * Cc + tid], acc);
    out[g * Cc + tid] = acc;
  }
}

// ------------------------------ launcher ------------------------------------
extern "C" void kernel_launch(void* const* d_in, const int* in_sizes, int n_in,
                              void* d_out, int out_size, void* d_ws, size_t ws_size,
                              hipStream_t stream) {
  const float* x    = (const float*)d_in[0];
  const float* ncn  = (const float*)d_in[1];
  const float* ecn  = (const float*)d_in[2];
  const float* W1   = (const float*)d_in[3];
  const float* b1   = (const float*)d_in[4];
  const float* g1   = (const float*)d_in[5];
  const float* be1  = (const float*)d_in[6];
  const float* W2   = (const float*)d_in[7];
  const float* b2   = (const float*)d_in[8];
  const float* Wc   = (const float*)d_in[9];
  const float* bc   = (const float*)d_in[10];
  const int*   ei   = (const int*)d_in[11];
  const int*   batch= (const int*)d_in[12];
  const int* src  = ei;
  const int* dstp = ei + Ee;

  // 3 big buffers (N*128 fp32 each) + partials + small/CSR tail: ~85 MB total
  float* fws = (float*)d_ws;
  float* bufA     = fws;                       // N*128
  float* bufB     = fws +  6400000;            // N*128
  float* h1       = fws + 12800000;            // N*128 (fixed)
  float* partial  = fws + 19200000;            // 256*PPAD (800 KB)
  float* scaleA   = partial + 256 * PPAD;      // 128
  float* shiftA   = scaleA + 128;              // 128
  float* pooled   = shiftA + 128;              // G*128
  float* gcnt     = pooled + Gg * 128;         // G (pad to 128)
  int*   deg      = (int*)(gcnt + 128);        // N
  int*   offs     = deg + Nn;                  // N+1 (pad)
  int*   cursor   = offs + Nn + 64;            // N
  int*   esrc     = cursor + Nn;               // E
  float* ew       = (float*)(esrc + Ee);       // E

  // build CSR (once per call, reused by all 3 layers)
  hipMemsetAsync(deg, 0, Nn * sizeof(int), stream);
  k_deg<<<1024, 256, 0, stream>>>(dstp, deg);
  k_scan<<<1, 1024, 0, stream>>>(deg, offs, cursor);
  k_fill<<<1024, 256, 0, stream>>>(src, dstp, ecn, cursor, esrc, ew);

  // Buffer schedule (agg is dead after gemm1, so gemm2 may overwrite it):
  //  l0: xin=x    agg=A  h1=C  xout=A
  //  l1: xin=A    agg=B  h1=C  xout=B
  //  l2: xin=B    agg=A  h1=C  xout=A
  const float* xin = x;
  for (int l = 0; l < Ll; ++l) {
    float* aggb = (l & 1) ? bufB : bufA;
    k_agg<<<(Nn + 3) / 4, 256, 0, stream>>>(xin, offs, esrc, ew, aggb);
    k_gemm1<<<NBLK1, 256, 0, stream>>>(aggb, ncn, xin, W1 + l * 128 * 128,
                                       b1 + l * 128, h1, partial);
    k_bnfin<<<128, 256, 0, stream>>>(partial, g1 + l * 128, be1 + l * 128,
                                     scaleA, shiftA);
    k_gemm2<<<NBLK1, 256, 0, stream>>>(h1, scaleA, shiftA, W2 + l * 128 * 128,
                                       b2 + l * 128, aggb);
    xin = aggb;
  }

  hipMemsetAsync(pooled, 0, (Gg * 128 + 128) * sizeof(float), stream);
  k_pool<<<(Nn + PCH * 4 - 1) / (PCH * 4), 256, 0, stream>>>(xin, batch, pooled, gcnt);
  k_head<<<Gg, 128, 0, stream>>>(pooled, gcnt, Wc, bc, (float*)d_out);
}

// Round 5
// 649.561 us; speedup vs baseline: 4.4448x; 1.3027x over previous
//
#include <hip/hip_runtime.h>

#define Nn 50000
#define Ee 800000
#define HD 128        // D == H == 128
#define Ll 3
#define Gg 128
#define Cc 10
#define BN_EPS 1e-5f
#define NBLK1 782     // ceil(Nn/64) — gemm row-tiles / BN partial rows
#define PPAD 800      // padded partial stride (feature-major layout)
#define NSCB 49       // ceil(Nn/1024) — scan blocks

// ----------------------------- CSR build ------------------------------------
__global__ void k_deg(const int* __restrict__ dst, int* __restrict__ deg) {
  int i = blockIdx.x * blockDim.x + threadIdx.x;
  int stride = gridDim.x * blockDim.x;
  for (int e = i; e < Ee; e += stride) atomicAdd(&deg[dst[e]], 1);
}

// ---- hierarchical scan: 49 parallel block-scans + wave carry scan + add ----
__global__ void k_scan1(const int* __restrict__ deg, int* __restrict__ offs,
                        int* __restrict__ bsum) {
  __shared__ int b0[1024], b1[1024];
  int tid = threadIdx.x;
  int i = blockIdx.x * 1024 + tid;
  int v = (i < Nn) ? deg[i] : 0;
  int* cur = b0; int* nxt = b1;
  cur[tid] = v;
  __syncthreads();
  for (int off = 1; off < 1024; off <<= 1) {
    int s = cur[tid] + ((tid >= off) ? cur[tid - off] : 0);
    nxt[tid] = s;
    __syncthreads();
    int* t = cur; cur = nxt; nxt = t;
  }
  if (i < Nn) offs[i] = cur[tid] - v;          // exclusive within block
  if (tid == 1023) bsum[blockIdx.x] = cur[1023];
}

__global__ void k_scan2(const int* __restrict__ bsum, int* __restrict__ carry) {
  int lane = threadIdx.x;                      // 64 threads, one wave
  int v = (lane < NSCB) ? bsum[lane] : 0;
  int s = v;
  for (int off = 1; off < 64; off <<= 1) {
    int t = __shfl_up(s, off, 64);
    if (lane >= off) s += t;
  }
  if (lane < NSCB) carry[lane] = s - v;        // exclusive carry per block
}

__global__ void k_scan3(const int* __restrict__ carry, int* __restrict__ offs,
                        int* __restrict__ cursor) {
  int i = blockIdx.x * 1024 + threadIdx.x;
  if (i < Nn) {
    int o = offs[i] + carry[blockIdx.x];
    offs[i] = o; cursor[i] = o;
  }
  if (i == 0) offs[Nn] = Ee;
}

__global__ void k_fill(const int* __restrict__ src, const int* __restrict__ dst,
                       const float* __restrict__ ec, int* __restrict__ cursor,
                       int* __restrict__ esrc, float* __restrict__ ew) {
  int i = blockIdx.x * blockDim.x + threadIdx.x;
  int stride = gridDim.x * blockDim.x;
  for (int e = i; e < Ee; e += stride) {
    int d = dst[e];
    int p = atomicAdd(&cursor[d], 1);
    esrc[p] = src[e];
    ew[p]   = ec[e];
  }
}

// -------------------- aggregation: gather (one wave per node) ---------------
// 2-edge unroll, independent accumulators: two row-loads in flight per iter.
__global__ void k_agg(const float* __restrict__ xin, const int* __restrict__ offs,
                      const int* __restrict__ esrc, const float* __restrict__ ew,
                      float* __restrict__ agg) {
  int wid = threadIdx.x >> 6, lane = threadIdx.x & 63;
  int n = blockIdx.x * 4 + wid;
  if (n >= Nn) return;
  int beg = offs[n], end = offs[n + 1];
  const float2* x2 = (const float2*)xin;
  float2 acc0 = make_float2(0.f, 0.f);
  float2 acc1 = make_float2(0.f, 0.f);
  int j = beg;
  for (; j + 1 < end; j += 2) {
    int s0 = esrc[j], s1 = esrc[j + 1];
    float w0 = ew[j], w1 = ew[j + 1];
    float2 v0 = x2[s0 * 64 + lane];
    float2 v1 = x2[s1 * 64 + lane];
    acc0.x = fmaf(v0.x, w0, acc0.x); acc0.y = fmaf(v0.y, w0, acc0.y);
    acc1.x = fmaf(v1.x, w1, acc1.x); acc1.y = fmaf(v1.y, w1, acc1.y);
  }
  if (j < end) {
    int s0 = esrc[j];
    float w0 = ew[j];
    float2 v0 = x2[s0 * 64 + lane];
    acc0.x = fmaf(v0.x, w0, acc0.x); acc0.y = fmaf(v0.y, w0, acc0.y);
  }
  acc0.x += acc1.x; acc0.y += acc1.y;
  ((float2*)agg)[n * 64 + lane] = acc0;
}

// -------------------- GEMM1: h1 = (agg*nc + x) @ W1 + b1, + BN partials -----
// 64-row tile, 256 threads, 8 rows x 4 cols each. W staged in TWO 32KB
// K-halves -> 66.5 KB LDS -> 2 blocks/CU (was 97KB -> 1 block/CU, 7.7% occ).
__launch_bounds__(256, 2)
__global__ void k_gemm1(const float* __restrict__ agg, const float* __restrict__ nc,
                        const float* __restrict__ xin, const float* __restrict__ W,
                        const float* __restrict__ bias, float* __restrict__ out,
                        float* __restrict__ partial) {
  __shared__ float Als[64][132];       // row-major, padded stride (33.8 KB)
  __shared__ float4 Wls[64 * 32];      // one K-half of W (32 KB)
  int tid = threadIdx.x;
  int row0 = blockIdx.x * 64;

  int c4 = tid & 31, rr = tid >> 5;
  for (int it = 0; it < 8; ++it) {
    int r = rr + it * 8;
    int grow = row0 + r;
    float4 a = make_float4(0.f, 0.f, 0.f, 0.f);
    if (grow < Nn) {
      float4 ag = ((const float4*)agg)[grow * 32 + c4];
      float4 xv = ((const float4*)xin)[grow * 32 + c4];
      float nv = nc[grow];
      a.x = fmaf(ag.x, nv, xv.x); a.y = fmaf(ag.y, nv, xv.y);
      a.z = fmaf(ag.z, nv, xv.z); a.w = fmaf(ag.w, nv, xv.w);
    }
    *(float4*)&Als[r][c4 * 4] = a;
  }

  int tx = tid & 31, ty = tid >> 5;
  float acc[8][4];
#pragma unroll
  for (int i = 0; i < 8; ++i)
#pragma unroll
    for (int j = 0; j < 4; ++j) acc[i][j] = 0.f;

  for (int h = 0; h < 2; ++h) {
    if (h) __syncthreads();                      // all done reading Wls[0]
    const float4* Wf4 = (const float4*)(W + h * 64 * 128);
    for (int i = tid; i < 2048; i += 256) Wls[i] = Wf4[i];
    __syncthreads();                             // W-half (and A on h=0) ready

#pragma unroll 4
    for (int kk = 0; kk < 64; kk += 4) {
      float4 b0 = Wls[(kk + 0) * 32 + tx];
      float4 b1v = Wls[(kk + 1) * 32 + tx];
      float4 b2v = Wls[(kk + 2) * 32 + tx];
      float4 b3v = Wls[(kk + 3) * 32 + tx];
#pragma unroll
      for (int i = 0; i < 8; ++i) {
        float4 av = *(const float4*)&Als[ty * 8 + i][h * 64 + kk];
        acc[i][0] = fmaf(av.x, b0.x, acc[i][0]); acc[i][1] = fmaf(av.x, b0.y, acc[i][1]);
        acc[i][2] = fmaf(av.x, b0.z, acc[i][2]); acc[i][3] = fmaf(av.x, b0.w, acc[i][3]);
        acc[i][0] = fmaf(av.y, b1v.x, acc[i][0]); acc[i][1] = fmaf(av.y, b1v.y, acc[i][1]);
        acc[i][2] = fmaf(av.y, b1v.z, acc[i][2]); acc[i][3] = fmaf(av.y, b1v.w, acc[i][3]);
        acc[i][0] = fmaf(av.z, b2v.x, acc[i][0]); acc[i][1] = fmaf(av.z, b2v.y, acc[i][1]);
        acc[i][2] = fmaf(av.z, b2v.z, acc[i][2]); acc[i][3] = fmaf(av.z, b2v.w, acc[i][3]);
        acc[i][0] = fmaf(av.w, b3v.x, acc[i][0]); acc[i][1] = fmaf(av.w, b3v.y, acc[i][1]);
        acc[i][2] = fmaf(av.w, b3v.z, acc[i][2]); acc[i][3] = fmaf(av.w, b3v.w, acc[i][3]);
      }
    }
  }

  float4 bcol = ((const float4*)bias)[tx];
  float s0 = 0, s1 = 0, s2 = 0, s3 = 0, q0 = 0, q1 = 0, q2 = 0, q3 = 0;
#pragma unroll
  for (int i = 0; i < 8; ++i) {
    int grow = row0 + ty * 8 + i;
    if (grow < Nn) {
      float4 o;
      o.x = acc[i][0] + bcol.x; o.y = acc[i][1] + bcol.y;
      o.z = acc[i][2] + bcol.z; o.w = acc[i][3] + bcol.w;
      ((float4*)out)[grow * 32 + tx] = o;
      s0 += o.x; s1 += o.y; s2 += o.z; s3 += o.w;
      q0 += o.x * o.x; q1 += o.y * o.y; q2 += o.z * o.z; q3 += o.w * o.w;
    }
  }

  // block-level reduction over ty (8 threads per column group) in LDS
  __syncthreads();                       // done reading Als
  float* red = (float*)Als;              // reuse: 256 threads x 8 floats
  red[tid * 8 + 0] = s0; red[tid * 8 + 1] = s1;
  red[tid * 8 + 2] = s2; red[tid * 8 + 3] = s3;
  red[tid * 8 + 4] = q0; red[tid * 8 + 5] = q1;
  red[tid * 8 + 6] = q2; red[tid * 8 + 7] = q3;
  __syncthreads();
  if (ty == 0) {
    float v[8];
#pragma unroll
    for (int j = 0; j < 8; ++j) v[j] = 0.f;
    for (int t = 0; t < 8; ++t) {
      int id = t * 32 + tx;
#pragma unroll
      for (int j = 0; j < 8; ++j) v[j] += red[id * 8 + j];
    }
    int blk = blockIdx.x;
#pragma unroll
    for (int j = 0; j < 4; ++j) {
      partial[(tx * 4 + j) * PPAD + blk]         = v[j];      // sums
      partial[(128 + tx * 4 + j) * PPAD + blk]   = v[4 + j];  // sumsq
    }
  }
}

// parallel partial reduce: one block per feature, coalesced strided reads.
__global__ void k_bnfin(const float* __restrict__ partial,
                        const float* __restrict__ g1, const float* __restrict__ be1,
                        float* __restrict__ scaleA, float* __restrict__ shiftA) {
  __shared__ float ss[256], qq[256];
  int f = blockIdx.x, t = threadIdx.x;
  float s = 0.f, q = 0.f;
  for (int b = t; b < NBLK1; b += 256) {
    s += partial[f * PPAD + b];
    q += partial[(128 + f) * PPAD + b];
  }
  ss[t] = s; qq[t] = q;
  __syncthreads();
  for (int off = 128; off > 0; off >>= 1) {
    if (t < off) { ss[t] += ss[t + off]; qq[t] += qq[t + off]; }
    __syncthreads();
  }
  if (t == 0) {
    const float inv = 1.0f / (float)Nn;
    float mu = ss[0] * inv;
    float var = fmaxf(qq[0] * inv - mu * mu, 0.f);
    float rs = rsqrtf(var + BN_EPS);
    float sc = rs * g1[f];
    scaleA[f] = sc;
    shiftA[f] = be1[f] - mu * sc;
  }
}

// -------- GEMM2: xout = relu( relu(h1*scaleA+shiftA) @ W2 + b2 ) ------------
__launch_bounds__(256, 2)
__global__ void k_gemm2(const float* __restrict__ h1, const float* __restrict__ scaleA,
                        const float* __restrict__ shiftA, const float* __restrict__ W,
                        const float* __restrict__ bias, float* __restrict__ out) {
  __shared__ float Als[64][132];
  __shared__ float4 Wls[64 * 32];
  int tid = threadIdx.x;
  int row0 = blockIdx.x * 64;

  int c4 = tid & 31, rr = tid >> 5;
  float4 sc = ((const float4*)scaleA)[c4];
  float4 sh = ((const float4*)shiftA)[c4];
  for (int it = 0; it < 8; ++it) {
    int r = rr + it * 8;
    int grow = row0 + r;
    float4 a = make_float4(0.f, 0.f, 0.f, 0.f);
    if (grow < Nn) {
      float4 h = ((const float4*)h1)[grow * 32 + c4];
      a.x = fmaxf(fmaf(h.x, sc.x, sh.x), 0.f);
      a.y = fmaxf(fmaf(h.y, sc.y, sh.y), 0.f);
      a.z = fmaxf(fmaf(h.z, sc.z, sh.z), 0.f);
      a.w = fmaxf(fmaf(h.w, sc.w, sh.w), 0.f);
    }
    *(float4*)&Als[r][c4 * 4] = a;
  }

  int tx = tid & 31, ty = tid >> 5;
  float acc[8][4];
#pragma unroll
  for (int i = 0; i < 8; ++i)
#pragma unroll
    for (int j = 0; j < 4; ++j) acc[i][j] = 0.f;

  for (int h = 0; h < 2; ++h) {
    if (h) __syncthreads();
    const float4* Wf4 = (const float4*)(W + h * 64 * 128);
    for (int i = tid; i < 2048; i += 256) Wls[i] = Wf4[i];
    __syncthreads();

#pragma unroll 4
    for (int kk = 0; kk < 64; kk += 4) {
      float4 b0 = Wls[(kk + 0) * 32 + tx];
      float4 b1v = Wls[(kk + 1) * 32 + tx];
      float4 b2v = Wls[(kk + 2) * 32 + tx];
      float4 b3v = Wls[(kk + 3) * 32 + tx];
#pragma unroll
      for (int i = 0; i < 8; ++i) {
        float4 av = *(const float4*)&Als[ty * 8 + i][h * 64 + kk];
        acc[i][0] = fmaf(av.x, b0.x, acc[i][0]); acc[i][1] = fmaf(av.x, b0.y, acc[i][1]);
        acc[i][2] = fmaf(av.x, b0.z, acc[i][2]); acc[i][3] = fmaf(av.x, b0.w, acc[i][3]);
        acc[i][0] = fmaf(av.y, b1v.x, acc[i][0]); acc[i][1] = fmaf(av.y, b1v.y, acc[i][1]);
        acc[i][2] = fmaf(av.y, b1v.z, acc[i][2]); acc[i][3] = fmaf(av.y, b1v.w, acc[i][3]);
        acc[i][0] = fmaf(av.z, b2v.x, acc[i][0]); acc[i][1] = fmaf(av.z, b2v.y, acc[i][1]);
        acc[i][2] = fmaf(av.z, b2v.z, acc[i][2]); acc[i][3] = fmaf(av.z, b2v.w, acc[i][3]);
        acc[i][0] = fmaf(av.w, b3v.x, acc[i][0]); acc[i][1] = fmaf(av.w, b3v.y, acc[i][1]);
        acc[i][2] = fmaf(av.w, b3v.z, acc[i][2]); acc[i][3] = fmaf(av.w, b3v.w, acc[i][3]);
      }
    }
  }

  float4 bcol = ((const float4*)bias)[tx];
#pragma unroll
  for (int i = 0; i < 8; ++i) {
    int grow = row0 + ty * 8 + i;
    if (grow < Nn) {
      float4 o;
      o.x = fmaxf(acc[i][0] + bcol.x, 0.f);
      o.y = fmaxf(acc[i][1] + bcol.y, 0.f);
      o.z = fmaxf(acc[i][2] + bcol.z, 0.f);
      o.w = fmaxf(acc[i][3] + bcol.w, 0.f);
      ((float4*)out)[grow * 32 + tx] = o;
    }
  }
}

// ------------------------------ pooling -------------------------------------
// batch is SORTED: one wave per 64 consecutive nodes, run-length accumulate in
// registers, flush to global atomics only on group change (~50x fewer atomics).
#define PCH 64
__global__ void k_pool(const float* __restrict__ xin, const int* __restrict__ batch,
                       float* __restrict__ pooled, float* __restrict__ gcnt) {
  int wid = threadIdx.x >> 6, lane = threadIdx.x & 63;
  int w = blockIdx.x * 4 + wid;
  int n0 = w * PCH;
  if (n0 >= Nn) return;
  int n1 = (n0 + PCH < Nn) ? n0 + PCH : Nn;
  const float2* x2 = (const float2*)xin;
  float2 acc = make_float2(0.f, 0.f);
  int cur = batch[n0];
  int cnt = 0;
  for (int n = n0; n < n1; ++n) {
    int g = batch[n];                    // wave-uniform
    if (g != cur) {
      atomicAdd(&pooled[cur * 128 + lane * 2 + 0], acc.x);
      atomicAdd(&pooled[cur * 128 + lane * 2 + 1], acc.y);
      if (lane == 0) atomicAdd(&gcnt[cur], (float)cnt);
      acc = make_float2(0.f, 0.f); cnt = 0; cur = g;
    }
    float2 v = x2[n * 64 + lane];
    acc.x += v.x; acc.y += v.y; ++cnt;
  }
  atomicAdd(&pooled[cur * 128 + lane * 2 + 0], acc.x);
  atomicAdd(&pooled[cur * 128 + lane * 2 + 1], acc.y);
  if (lane == 0) atomicAdd(&gcnt[cur], (float)cnt);
}

__global__ void k_head(const float* __restrict__ pooled, const float* __restrict__ gcnt,
                       const float* __restrict__ Wc, const float* __restrict__ bc,
                       float* __restrict__ out) {
  __shared__ float p[128];
  int g = blockIdx.x, tid = threadIdx.x;
  p[tid] = pooled[g * 128 + tid] / fmaxf(gcnt[g], 1.0f);
  __syncthreads();
  if (tid < Cc) {
    float acc = bc[tid];
    for (int k = 0; k < 128; ++k) acc = fmaf(p[k], Wc[k * Cc + tid], acc);
    out[g * Cc + tid] = acc;
  }
}

// ------------------------------ launcher ------------------------------------
extern "C" void kernel_launch(void* const* d_in, const int* in_sizes, int n_in,
                              void* d_out, int out_size, void* d_ws, size_t ws_size,
                              hipStream_t stream) {
  const float* x    = (const float*)d_in[0];
  const float* ncn  = (const float*)d_in[1];
  const float* ecn  = (const float*)d_in[2];
  const float* W1   = (const float*)d_in[3];
  const float* b1   = (const float*)d_in[4];
  const float* g1   = (const float*)d_in[5];
  const float* be1  = (const float*)d_in[6];
  const float* W2   = (const float*)d_in[7];
  const float* b2   = (const float*)d_in[8];
  const float* Wc   = (const float*)d_in[9];
  const float* bc   = (const float*)d_in[10];
  const int*   ei   = (const int*)d_in[11];
  const int*   batch= (const int*)d_in[12];
  const int* src  = ei;
  const int* dstp = ei + Ee;

  // 3 big buffers (N*128 fp32 each) + partials + small/CSR tail: ~85 MB total
  float* fws = (float*)d_ws;
  float* bufA     = fws;                       // N*128
  float* bufB     = fws +  6400000;            // N*128
  float* h1       = fws + 12800000;            // N*128 (fixed)
  float* partial  = fws + 19200000;            // 256*PPAD (800 KB)
  float* scaleA   = partial + 256 * PPAD;      // 128
  float* shiftA   = scaleA + 128;              // 128
  float* pooled   = shiftA + 128;              // G*128
  float* gcnt     = pooled + Gg * 128;         // G (pad to 128)
  int*   deg      = (int*)(gcnt + 128);        // N
  int*   offs     = deg + Nn;                  // N+1 (pad)
  int*   cursor   = offs + Nn + 64;            // N
  int*   esrc     = cursor + Nn;               // E
  float* ew       = (float*)(esrc + Ee);       // E
  int*   bsum     = (int*)(ew + Ee);           // NSCB (pad 64)
  int*   carry    = bsum + 64;                 // NSCB (pad 64)

  // build CSR (once per call, reused by all 3 layers)
  hipMemsetAsync(deg, 0, Nn * sizeof(int), stream);
  k_deg<<<1024, 256, 0, stream>>>(dstp, deg);
  k_scan1<<<NSCB, 1024, 0, stream>>>(deg, offs, bsum);
  k_scan2<<<1, 64, 0, stream>>>(bsum, carry);
  k_scan3<<<NSCB, 1024, 0, stream>>>(carry, offs, cursor);
  k_fill<<<1024, 256, 0, stream>>>(src, dstp, ecn, cursor, esrc, ew);

  // Buffer schedule (agg is dead after gemm1, so gemm2 may overwrite it):
  //  l0: xin=x    agg=A  h1=C  xout=A
  //  l1: xin=A    agg=B  h1=C  xout=B
  //  l2: xin=B    agg=A  h1=C  xout=A
  const float* xin = x;
  for (int l = 0; l < Ll; ++l) {
    float* aggb = (l & 1) ? bufB : bufA;
    k_agg<<<(Nn + 3) / 4, 256, 0, stream>>>(xin, offs, esrc, ew, aggb);
    k_gemm1<<<NBLK1, 256, 0, stream>>>(aggb, ncn, xin, W1 + l * 128 * 128,
                                       b1 + l * 128, h1, partial);
    k_bnfin<<<128, 256, 0, stream>>>(partial, g1 + l * 128, be1 + l * 128,
                                     scaleA, shiftA);
    k_gemm2<<<NBLK1, 256, 0, stream>>>(h1, scaleA, shiftA, W2 + l * 128 * 128,
                                       b2 + l * 128, aggb);
    xin = aggb;
  }

  hipMemsetAsync(pooled, 0, (Gg * 128 + 128) * sizeof(float), stream);
  k_pool<<<(Nn + PCH * 4 - 1) / (PCH * 4), 256, 0, stream>>>(xin, batch, pooled, gcnt);
  k_head<<<Gg, 128, 0, stream>>>(pooled, gcnt, Wc, bc, (float*)d_out);
}

// Round 6
// 583.885 us; speedup vs baseline: 4.9447x; 1.1125x over previous
//
#include <hip/hip_runtime.h>

#define Nn 50000
#define Ee 800000
#define HD 128        // D == H == 128
#define Ll 3
#define Gg 128
#define Cc 10
#define BN_EPS 1e-5f
#define NBLK1 782     // ceil(Nn/64) — gemm row-tiles / BN partial rows
#define PPAD 800      // padded partial stride (feature-major layout)
#define NSCB 49       // ceil(Nn/1024) — scan blocks

typedef __attribute__((ext_vector_type(8))) __bf16 bf16x8;
typedef __attribute__((ext_vector_type(4))) float f32x4;

// ----------------------------- CSR build ------------------------------------
__global__ void k_deg(const int* __restrict__ dst, int* __restrict__ deg) {
  int i = blockIdx.x * blockDim.x + threadIdx.x;
  int stride = gridDim.x * blockDim.x;
  for (int e = i; e < Ee; e += stride) atomicAdd(&deg[dst[e]], 1);
}

__global__ void k_scan1(const int* __restrict__ deg, int* __restrict__ offs,
                        int* __restrict__ bsum) {
  __shared__ int b0[1024], b1[1024];
  int tid = threadIdx.x;
  int i = blockIdx.x * 1024 + tid;
  int v = (i < Nn) ? deg[i] : 0;
  int* cur = b0; int* nxt = b1;
  cur[tid] = v;
  __syncthreads();
  for (int off = 1; off < 1024; off <<= 1) {
    int s = cur[tid] + ((tid >= off) ? cur[tid - off] : 0);
    nxt[tid] = s;
    __syncthreads();
    int* t = cur; cur = nxt; nxt = t;
  }
  if (i < Nn) offs[i] = cur[tid] - v;          // exclusive within block
  if (tid == 1023) bsum[blockIdx.x] = cur[1023];
}

__global__ void k_scan2(const int* __restrict__ bsum, int* __restrict__ carry) {
  int lane = threadIdx.x;                      // 64 threads, one wave
  int v = (lane < NSCB) ? bsum[lane] : 0;
  int s = v;
  for (int off = 1; off < 64; off <<= 1) {
    int t = __shfl_up(s, off, 64);
    if (lane >= off) s += t;
  }
  if (lane < NSCB) carry[lane] = s - v;        // exclusive carry per block
}

__global__ void k_scan3(const int* __restrict__ carry, int* __restrict__ offs,
                        int* __restrict__ cursor) {
  int i = blockIdx.x * 1024 + threadIdx.x;
  if (i < Nn) {
    int o = offs[i] + carry[blockIdx.x];
    offs[i] = o; cursor[i] = o;
  }
  if (i == 0) offs[Nn] = Ee;
}

// packed edge fill: one 8B store per edge (was 2x 4B into separate arrays)
__global__ void k_fill(const int* __restrict__ src, const int* __restrict__ dst,
                       const float* __restrict__ ec, int* __restrict__ cursor,
                       int2* __restrict__ epk) {
  int i = blockIdx.x * blockDim.x + threadIdx.x;
  int stride = gridDim.x * blockDim.x;
  for (int e = i; e < Ee; e += stride) {
    int d = dst[e];
    int p = atomicAdd(&cursor[d], 1);
    epk[p] = make_int2(src[e], __float_as_int(ec[e]));
  }
}

// ---- W prep: Wt_hi/lo[n][k] bf16 split of W[k][n], 6 matrices (3xW1,3xW2) --
__global__ void k_wprep(const float* __restrict__ W1, const float* __restrict__ W2,
                        __bf16* __restrict__ wtHi, __bf16* __restrict__ wtLo) {
  int mat = blockIdx.x >> 3;                    // 0..5
  int chunk = blockIdx.x & 7;                   // 0..7 (2048 elems each)
  const float* W = (mat < 3) ? (W1 + mat * 16384) : (W2 + (mat - 3) * 16384);
  __bf16* hi = wtHi + mat * 16384;
  __bf16* lo = wtLo + mat * 16384;
  for (int t = threadIdx.x; t < 2048; t += blockDim.x) {
    int idx = chunk * 2048 + t;                 // Wt index: n*128 + k
    int n = idx >> 7, k = idx & 127;
    float v = W[k * 128 + n];
    __bf16 h = (__bf16)v;
    hi[idx] = h;
    lo[idx] = (__bf16)(v - (float)h);
  }
}

// -------------------- aggregation: gather (one wave per node) ---------------
// 4-edge unroll, packed int2 edges: 4 row-loads in flight per iter.
__global__ void k_agg(const float* __restrict__ xin, const int* __restrict__ offs,
                      const int2* __restrict__ epk, float* __restrict__ agg) {
  int wid = threadIdx.x >> 6, lane = threadIdx.x & 63;
  int n = blockIdx.x * 4 + wid;
  if (n >= Nn) return;
  int beg = offs[n], end = offs[n + 1];
  const float2* x2 = (const float2*)xin;
  float2 a0 = make_float2(0.f, 0.f), a1 = make_float2(0.f, 0.f);
  float2 a2 = make_float2(0.f, 0.f), a3 = make_float2(0.f, 0.f);
  int j = beg;
  for (; j + 3 < end; j += 4) {
    int2 e0 = epk[j], e1 = epk[j + 1], e2 = epk[j + 2], e3 = epk[j + 3];
    float2 v0 = x2[e0.x * 64 + lane];
    float2 v1 = x2[e1.x * 64 + lane];
    float2 v2 = x2[e2.x * 64 + lane];
    float2 v3 = x2[e3.x * 64 + lane];
    float w0 = __int_as_float(e0.y), w1 = __int_as_float(e1.y);
    float w2 = __int_as_float(e2.y), w3 = __int_as_float(e3.y);
    a0.x = fmaf(v0.x, w0, a0.x); a0.y = fmaf(v0.y, w0, a0.y);
    a1.x = fmaf(v1.x, w1, a1.x); a1.y = fmaf(v1.y, w1, a1.y);
    a2.x = fmaf(v2.x, w2, a2.x); a2.y = fmaf(v2.y, w2, a2.y);
    a3.x = fmaf(v3.x, w3, a3.x); a3.y = fmaf(v3.y, w3, a3.y);
  }
  for (; j < end; ++j) {
    int2 e = epk[j];
    float2 v = x2[e.x * 64 + lane];
    float w = __int_as_float(e.y);
    a0.x = fmaf(v.x, w, a0.x); a0.y = fmaf(v.y, w, a0.y);
  }
  a0.x += a1.x + a2.x + a3.x;
  a0.y += a1.y + a2.y + a3.y;
  ((float2*)agg)[n * 64 + lane] = a0;
}

// ---------------- MFMA hi/lo split helpers ----------------------------------
__device__ __forceinline__ void split8(const float* a, bf16x8& hi, bf16x8& lo) {
#pragma unroll
  for (int j = 0; j < 8; ++j) {
    float v = a[j];
    __bf16 h = (__bf16)v;
    hi[j] = h;
    lo[j] = (__bf16)(v - (float)h);
  }
}

// -------------------- GEMM1 (MFMA): h1 = (agg*nc + x) @ W1 + b1 + BN stats --
// 128 thr = 2 waves; block tile 64 rows x 128 cols; wave tile 64x64 =
// 4x4 tiles of 16x16x32 MFMA. hi/lo split: 3 MFMA per tile per k-step.
// A from global fp32 (fused agg*nc+x), B from pre-split Wt (L2-resident).
__launch_bounds__(128)
__global__ void k_gemm1(const float* __restrict__ agg, const float* __restrict__ nc,
                        const float* __restrict__ xin,
                        const __bf16* __restrict__ wtHi, const __bf16* __restrict__ wtLo,
                        const float* __restrict__ bias, float* __restrict__ out,
                        float* __restrict__ partial) {
  int tid = threadIdx.x;
  int w = tid >> 6, l = tid & 63;
  int row0 = blockIdx.x * 64;
  int l15 = l & 15, lg = l >> 4;
  int colw = w * 64;
  int krow = lg * 8;

  f32x4 acc[4][4];
#pragma unroll
  for (int m = 0; m < 4; ++m)
#pragma unroll
    for (int n = 0; n < 4; ++n) acc[m][n] = (f32x4){0.f, 0.f, 0.f, 0.f};

  int rowA[4]; bool rv[4]; float ncv[4];
#pragma unroll
  for (int m = 0; m < 4; ++m) {
    rowA[m] = row0 + m * 16 + l15;
    rv[m] = rowA[m] < Nn;
    ncv[m] = rv[m] ? nc[rowA[m]] : 0.f;
  }

#pragma unroll
  for (int ks = 0; ks < 4; ++ks) {
    int k0 = ks * 32 + krow;
    bf16x8 aHi[4], aLo[4];
#pragma unroll
    for (int m = 0; m < 4; ++m) {
      float av[8];
      if (rv[m]) {
        const float* ap = agg + rowA[m] * 128 + k0;
        const float* xp = xin + rowA[m] * 128 + k0;
        f32x4 g0 = *(const f32x4*)ap, g1 = *(const f32x4*)(ap + 4);
        f32x4 x0 = *(const f32x4*)xp, x1 = *(const f32x4*)(xp + 4);
#pragma unroll
        for (int jj = 0; jj < 4; ++jj) {
          av[jj]     = fmaf(g0[jj], ncv[m], x0[jj]);
          av[4 + jj] = fmaf(g1[jj], ncv[m], x1[jj]);
        }
      } else {
#pragma unroll
        for (int jj = 0; jj < 8; ++jj) av[jj] = 0.f;
      }
      split8(av, aHi[m], aLo[m]);
    }
    bf16x8 bHi[4], bLo[4];
#pragma unroll
    for (int n = 0; n < 4; ++n) {
      int c = colw + n * 16 + l15;
      bHi[n] = *(const bf16x8*)(wtHi + c * 128 + k0);
      bLo[n] = *(const bf16x8*)(wtLo + c * 128 + k0);
    }
#pragma unroll
    for (int m = 0; m < 4; ++m)
#pragma unroll
      for (int n = 0; n < 4; ++n) {
        acc[m][n] = __builtin_amdgcn_mfma_f32_16x16x32_bf16(aHi[m], bHi[n], acc[m][n], 0, 0, 0);
        acc[m][n] = __builtin_amdgcn_mfma_f32_16x16x32_bf16(aLo[m], bHi[n], acc[m][n], 0, 0, 0);
        acc[m][n] = __builtin_amdgcn_mfma_f32_16x16x32_bf16(aHi[m], bLo[n], acc[m][n], 0, 0, 0);
      }
  }

  // epilogue: bias, store, BN column stats
  float s[4] = {0.f, 0.f, 0.f, 0.f}, q[4] = {0.f, 0.f, 0.f, 0.f};
#pragma unroll
  for (int n = 0; n < 4; ++n) {
    int c = colw + n * 16 + l15;
    float bv = bias[c];
#pragma unroll
    for (int m = 0; m < 4; ++m) {
      int rbase = row0 + m * 16 + lg * 4;
#pragma unroll
      for (int r = 0; r < 4; ++r) {
        int rr = rbase + r;
        if (rr < Nn) {
          float o = acc[m][n][r] + bv;
          out[rr * 128 + c] = o;
          s[n] += o; q[n] += o * o;
        }
      }
    }
  }
  // reduce over the 4 lane-groups (same column lives in lanes l, l^16, l^32)
#pragma unroll
  for (int n = 0; n < 4; ++n) {
    s[n] += __shfl_xor(s[n], 16, 64); q[n] += __shfl_xor(q[n], 16, 64);
    s[n] += __shfl_xor(s[n], 32, 64); q[n] += __shfl_xor(q[n], 32, 64);
  }
  if (lg == 0) {
    int blk = blockIdx.x;
#pragma unroll
    for (int n = 0; n < 4; ++n) {
      int f = colw + n * 16 + l15;
      partial[f * PPAD + blk] = s[n];
      partial[(128 + f) * PPAD + blk] = q[n];
    }
  }
}

// parallel partial reduce: one block per feature, coalesced strided reads.
__global__ void k_bnfin(const float* __restrict__ partial,
                        const float* __restrict__ g1, const float* __restrict__ be1,
                        float* __restrict__ scaleA, float* __restrict__ shiftA) {
  __shared__ float ss[256], qq[256];
  int f = blockIdx.x, t = threadIdx.x;
  float s = 0.f, q = 0.f;
  for (int b = t; b < NBLK1; b += 256) {
    s += partial[f * PPAD + b];
    q += partial[(128 + f) * PPAD + b];
  }
  ss[t] = s; qq[t] = q;
  __syncthreads();
  for (int off = 128; off > 0; off >>= 1) {
    if (t < off) { ss[t] += ss[t + off]; qq[t] += qq[t + off]; }
    __syncthreads();
  }
  if (t == 0) {
    const float inv = 1.0f / (float)Nn;
    float mu = ss[0] * inv;
    float var = fmaxf(qq[0] * inv - mu * mu, 0.f);
    float rs = rsqrtf(var + BN_EPS);
    float sc = rs * g1[f];
    scaleA[f] = sc;
    shiftA[f] = be1[f] - mu * sc;
  }
}

// ---- GEMM2 (MFMA): xout = relu( relu(h1*scaleA+shiftA) @ W2 + b2 ) ---------
__launch_bounds__(128)
__global__ void k_gemm2(const float* __restrict__ h1, const float* __restrict__ scaleA,
                        const float* __restrict__ shiftA,
                        const __bf16* __restrict__ wtHi, const __bf16* __restrict__ wtLo,
                        const float* __restrict__ bias, float* __restrict__ out) {
  int tid = threadIdx.x;
  int w = tid >> 6, l = tid & 63;
  int row0 = blockIdx.x * 64;
  int l15 = l & 15, lg = l >> 4;
  int colw = w * 64;
  int krow = lg * 8;

  f32x4 acc[4][4];
#pragma unroll
  for (int m = 0; m < 4; ++m)
#pragma unroll
    for (int n = 0; n < 4; ++n) acc[m][n] = (f32x4){0.f, 0.f, 0.f, 0.f};

  int rowA[4]; bool rv[4];
#pragma unroll
  for (int m = 0; m < 4; ++m) {
    rowA[m] = row0 + m * 16 + l15;
    rv[m] = rowA[m] < Nn;
  }

#pragma unroll
  for (int ks = 0; ks < 4; ++ks) {
    int k0 = ks * 32 + krow;
    f32x4 sc0 = *(const f32x4*)(scaleA + k0), sc1 = *(const f32x4*)(scaleA + k0 + 4);
    f32x4 sh0 = *(const f32x4*)(shiftA + k0), sh1 = *(const f32x4*)(shiftA + k0 + 4);
    bf16x8 aHi[4], aLo[4];
#pragma unroll
    for (int m = 0; m < 4; ++m) {
      float av[8];
      if (rv[m]) {
        const float* hp = h1 + rowA[m] * 128 + k0;
        f32x4 h0 = *(const f32x4*)hp, h1v = *(const f32x4*)(hp + 4);
#pragma unroll
        for (int jj = 0; jj < 4; ++jj) {
          av[jj]     = fmaxf(fmaf(h0[jj],  sc0[jj], sh0[jj]), 0.f);
          av[4 + jj] = fmaxf(fmaf(h1v[jj], sc1[jj], sh1[jj]), 0.f);
        }
      } else {
#pragma unroll
        for (int jj = 0; jj < 8; ++jj) av[jj] = 0.f;
      }
      split8(av, aHi[m], aLo[m]);
    }
    bf16x8 bHi[4], bLo[4];
#pragma unroll
    for (int n = 0; n < 4; ++n) {
      int c = colw + n * 16 + l15;
      bHi[n] = *(const bf16x8*)(wtHi + c * 128 + k0);
      bLo[n] = *(const bf16x8*)(wtLo + c * 128 + k0);
    }
#pragma unroll
    for (int m = 0; m < 4; ++m)
#pragma unroll
      for (int n = 0; n < 4; ++n) {
        acc[m][n] = __builtin_amdgcn_mfma_f32_16x16x32_bf16(aHi[m], bHi[n], acc[m][n], 0, 0, 0);
        acc[m][n] = __builtin_amdgcn_mfma_f32_16x16x32_bf16(aLo[m], bHi[n], acc[m][n], 0, 0, 0);
        acc[m][n] = __builtin_amdgcn_mfma_f32_16x16x32_bf16(aHi[m], bLo[n], acc[m][n], 0, 0, 0);
      }
  }

#pragma unroll
  for (int n = 0; n < 4; ++n) {
    int c = colw + n * 16 + l15;
    float bv = bias[c];
#pragma unroll
    for (int m = 0; m < 4; ++m) {
      int rbase = row0 + m * 16 + lg * 4;
#pragma unroll
      for (int r = 0; r < 4; ++r) {
        int rr = rbase + r;
        if (rr < Nn) out[rr * 128 + c] = fmaxf(acc[m][n][r] + bv, 0.f);
      }
    }
  }
}

// ------------------------------ pooling -------------------------------------
#define PCH 64
__global__ void k_pool(const float* __restrict__ xin, const int* __restrict__ batch,
                       float* __restrict__ pooled, float* __restrict__ gcnt) {
  int wid = threadIdx.x >> 6, lane = threadIdx.x & 63;
  int w = blockIdx.x * 4 + wid;
  int n0 = w * PCH;
  if (n0 >= Nn) return;
  int n1 = (n0 + PCH < Nn) ? n0 + PCH : Nn;
  const float2* x2 = (const float2*)xin;
  float2 acc = make_float2(0.f, 0.f);
  int cur = batch[n0];
  int cnt = 0;
  for (int n = n0; n < n1; ++n) {
    int g = batch[n];                    // wave-uniform
    if (g != cur) {
      atomicAdd(&pooled[cur * 128 + lane * 2 + 0], acc.x);
      atomicAdd(&pooled[cur * 128 + lane * 2 + 1], acc.y);
      if (lane == 0) atomicAdd(&gcnt[cur], (float)cnt);
      acc = make_float2(0.f, 0.f); cnt = 0; cur = g;
    }
    float2 v = x2[n * 64 + lane];
    acc.x += v.x; acc.y += v.y; ++cnt;
  }
  atomicAdd(&pooled[cur * 128 + lane * 2 + 0], acc.x);
  atomicAdd(&pooled[cur * 128 + lane * 2 + 1], acc.y);
  if (lane == 0) atomicAdd(&gcnt[cur], (float)cnt);
}

__global__ void k_head(const float* __restrict__ pooled, const float* __restrict__ gcnt,
                       const float* __restrict__ Wc, const float* __restrict__ bc,
                       float* __restrict__ out) {
  __shared__ float p[128];
  int g = blockIdx.x, tid = threadIdx.x;
  p[tid] = pooled[g * 128 + tid] / fmaxf(gcnt[g], 1.0f);
  __syncthreads();
  if (tid < Cc) {
    float acc = bc[tid];
    for (int k = 0; k < 128; ++k) acc = fmaf(p[k], Wc[k * Cc + tid], acc);
    out[g * Cc + tid] = acc;
  }
}

// ------------------------------ launcher ------------------------------------
extern "C" void kernel_launch(void* const* d_in, const int* in_sizes, int n_in,
                              void* d_out, int out_size, void* d_ws, size_t ws_size,
                              hipStream_t stream) {
  const float* x    = (const float*)d_in[0];
  const float* ncn  = (const float*)d_in[1];
  const float* ecn  = (const float*)d_in[2];
  const float* W1   = (const float*)d_in[3];
  const float* b1   = (const float*)d_in[4];
  const float* g1   = (const float*)d_in[5];
  const float* be1  = (const float*)d_in[6];
  const float* W2   = (const float*)d_in[7];
  const float* b2   = (const float*)d_in[8];
  const float* Wc   = (const float*)d_in[9];
  const float* bc   = (const float*)d_in[10];
  const int*   ei   = (const int*)d_in[11];
  const int*   batch= (const int*)d_in[12];
  const int* src  = ei;
  const int* dstp = ei + Ee;

  float* fws = (float*)d_ws;
  float* bufA     = fws;                       // N*128
  float* bufB     = fws +  6400000;            // N*128
  float* h1       = fws + 12800000;            // N*128 (fixed)
  float* partial  = fws + 19200000;            // 256*PPAD (800 KB)
  float* scaleA   = partial + 256 * PPAD;      // 128
  float* shiftA   = scaleA + 128;              // 128
  float* pooled   = shiftA + 128;              // G*128
  float* gcnt     = pooled + Gg * 128;         // 128
  int*   ib       = (int*)(gcnt + 128);
  int*   deg      = ib;                        // N
  int*   offs     = deg + Nn;                  // N+64
  int*   cursor   = offs + Nn + 64;            // N
  int*   bsum     = cursor + Nn;               // 64
  int*   carry    = bsum + 64;                 // 64
  int2*  epk      = (int2*)(carry + 64);       // E  (8-byte aligned)
  __bf16* wtHi    = (__bf16*)(epk + Ee);       // 6*16384 bf16
  __bf16* wtLo    = wtHi + 6 * 16384;          // 6*16384 bf16

  // W prep + CSR build (once per call, reused by all 3 layers)
  k_wprep<<<48, 256, 0, stream>>>(W1, W2, wtHi, wtLo);
  hipMemsetAsync(deg, 0, Nn * sizeof(int), stream);
  k_deg<<<1024, 256, 0, stream>>>(dstp, deg);
  k_scan1<<<NSCB, 1024, 0, stream>>>(deg, offs, bsum);
  k_scan2<<<1, 64, 0, stream>>>(bsum, carry);
  k_scan3<<<NSCB, 1024, 0, stream>>>(carry, offs, cursor);
  k_fill<<<1024, 256, 0, stream>>>(src, dstp, ecn, cursor, epk);

  // Buffer schedule (agg dead after gemm1 -> gemm2 overwrites it)
  const float* xin = x;
  for (int l = 0; l < Ll; ++l) {
    float* aggb = (l & 1) ? bufB : bufA;
    k_agg<<<(Nn + 3) / 4, 256, 0, stream>>>(xin, offs, epk, aggb);
    k_gemm1<<<NBLK1, 128, 0, stream>>>(aggb, ncn, xin,
                                       wtHi + l * 16384, wtLo + l * 16384,
                                       b1 + l * 128, h1, partial);
    k_bnfin<<<128, 256, 0, stream>>>(partial, g1 + l * 128, be1 + l * 128,
                                     scaleA, shiftA);
    k_gemm2<<<NBLK1, 128, 0, stream>>>(h1, scaleA, shiftA,
                                       wtHi + (3 + l) * 16384, wtLo + (3 + l) * 16384,
                                       b2 + l * 128, aggb);
    xin = aggb;
  }

  hipMemsetAsync(pooled, 0, (Gg * 128 + 128) * sizeof(float), stream);
  k_pool<<<(Nn + PCH * 4 - 1) / (PCH * 4), 256, 0, stream>>>(xin, batch, pooled, gcnt);
  k_head<<<Gg, 128, 0, stream>>>(pooled, gcnt, Wc, bc, (float*)d_out);
}

// Round 7
// 536.564 us; speedup vs baseline: 5.3808x; 1.0882x over previous
//
#include <hip/hip_runtime.h>
#include <hip/hip_fp16.h>

#define Nn 50000
#define Ee 800000
#define HD 128        // D == H == 128
#define Ll 3
#define Gg 128
#define Cc 10
#define BN_EPS 1e-5f
#define NBLK1 782     // ceil(Nn/64) — gemm row-tiles / BN partial rows
#define PPAD 800      // padded partial stride (feature-major layout)
#define NSCB 49       // ceil(Nn/1024) — scan blocks

typedef __attribute__((ext_vector_type(8))) __bf16 bf16x8;
typedef __attribute__((ext_vector_type(4))) __bf16 bf16x4;
typedef __attribute__((ext_vector_type(4))) float f32x4;

// ----------------------------- CSR build ------------------------------------
// 4 independent atomic chains per thread (latency hiding for L2 atomics)
__global__ void k_deg(const int* __restrict__ dst, int* __restrict__ deg) {
  int i = blockIdx.x * blockDim.x + threadIdx.x;
  int base = i * 4;
  if (base >= Ee) return;
#pragma unroll
  for (int j = 0; j < 4; ++j) {
    int e = base + j;
    if (e < Ee) atomicAdd(&deg[dst[e]], 1);
  }
}

__global__ void k_scan1(const int* __restrict__ deg, int* __restrict__ offs,
                        int* __restrict__ bsum) {
  __shared__ int b0[1024], b1[1024];
  int tid = threadIdx.x;
  int i = blockIdx.x * 1024 + tid;
  int v = (i < Nn) ? deg[i] : 0;
  int* cur = b0; int* nxt = b1;
  cur[tid] = v;
  __syncthreads();
  for (int off = 1; off < 1024; off <<= 1) {
    int s = cur[tid] + ((tid >= off) ? cur[tid - off] : 0);
    nxt[tid] = s;
    __syncthreads();
    int* t = cur; cur = nxt; nxt = t;
  }
  if (i < Nn) offs[i] = cur[tid] - v;          // exclusive within block
  if (tid == 1023) bsum[blockIdx.x] = cur[1023];
}

__global__ void k_scan2(const int* __restrict__ bsum, int* __restrict__ carry) {
  int lane = threadIdx.x;                      // 64 threads, one wave
  int v = (lane < NSCB) ? bsum[lane] : 0;
  int s = v;
  for (int off = 1; off < 64; off <<= 1) {
    int t = __shfl_up(s, off, 64);
    if (lane >= off) s += t;
  }
  if (lane < NSCB) carry[lane] = s - v;        // exclusive carry per block
}

__global__ void k_scan3(const int* __restrict__ carry, int* __restrict__ offs,
                        int* __restrict__ cursor) {
  int i = blockIdx.x * 1024 + threadIdx.x;
  if (i < Nn) {
    int o = offs[i] + carry[blockIdx.x];
    offs[i] = o; cursor[i] = o;
  }
  if (i == 0) offs[Nn] = Ee;
}

// packed edge fill: (src:16 | fp16 weight:16) = 4B/edge, 4 chains in flight
__global__ void k_fill(const int* __restrict__ src, const int* __restrict__ dst,
                       const float* __restrict__ ec, int* __restrict__ cursor,
                       unsigned int* __restrict__ epk) {
  int i = blockIdx.x * blockDim.x + threadIdx.x;
  int base = i * 4;
  if (base >= Ee) return;
  int d[4], s[4], p[4]; unsigned short hb[4]; bool ok[4];
#pragma unroll
  for (int j = 0; j < 4; ++j) {
    int e = base + j;
    ok[j] = e < Ee;
    if (ok[j]) {
      d[j] = dst[e]; s[j] = src[e];
      hb[j] = __half_as_ushort(__float2half(ec[e]));
    }
  }
#pragma unroll
  for (int j = 0; j < 4; ++j)
    if (ok[j]) p[j] = atomicAdd(&cursor[d[j]], 1);
#pragma unroll
  for (int j = 0; j < 4; ++j)
    if (ok[j]) epk[p[j]] = ((unsigned int)s[j] << 16) | hb[j];
}

// ---- x -> bf16 copy (for the gather path) ----------------------------------
__global__ void k_xcast(const float* __restrict__ x, __bf16* __restrict__ xb) {
  int i = blockIdx.x * blockDim.x + threadIdx.x;
  int stride = gridDim.x * blockDim.x;
  const int n4 = Nn * 32;                      // Nn*128/4
  for (int t = i; t < n4; t += stride) {
    f32x4 v = ((const f32x4*)x)[t];
    bf16x4 b;
#pragma unroll
    for (int j = 0; j < 4; ++j) b[j] = (__bf16)v[j];
    ((bf16x4*)xb)[t] = b;
  }
}

// ---- W prep: Wt_hi/lo[n][k] bf16 split of W[k][n], 6 matrices (3xW1,3xW2) --
__global__ void k_wprep(const float* __restrict__ W1, const float* __restrict__ W2,
                        __bf16* __restrict__ wtHi, __bf16* __restrict__ wtLo) {
  int mat = blockIdx.x >> 3;                    // 0..5
  int chunk = blockIdx.x & 7;                   // 0..7 (2048 elems each)
  const float* W = (mat < 3) ? (W1 + mat * 16384) : (W2 + (mat - 3) * 16384);
  __bf16* hi = wtHi + mat * 16384;
  __bf16* lo = wtLo + mat * 16384;
  for (int t = threadIdx.x; t < 2048; t += blockDim.x) {
    int idx = chunk * 2048 + t;                 // Wt index: n*128 + k
    int n = idx >> 7, k = idx & 127;
    float v = W[k * 128 + n];
    __bf16 h = (__bf16)v;
    hi[idx] = h;
    lo[idx] = (__bf16)(v - (float)h);
  }
}

// -------------------- aggregation: gather (one wave per node) ---------------
// bf16 rows (256B/row), packed 4B edges, 4-edge unroll, fp32 accumulate.
__global__ void k_agg(const __bf16* __restrict__ xb, const int* __restrict__ offs,
                      const unsigned int* __restrict__ epk, float* __restrict__ agg) {
  int wid = threadIdx.x >> 6, lane = threadIdx.x & 63;
  int n = blockIdx.x * 4 + wid;
  if (n >= Nn) return;
  int beg = offs[n], end = offs[n + 1];
  const unsigned int* x2 = (const unsigned int*)xb;   // 2 bf16 per uint, row=64
  float ax0 = 0.f, ay0 = 0.f, ax1 = 0.f, ay1 = 0.f;
  float ax2 = 0.f, ay2 = 0.f, ax3 = 0.f, ay3 = 0.f;
  int j = beg;
  for (; j + 3 < end; j += 4) {
    unsigned int e0 = epk[j], e1 = epk[j + 1], e2 = epk[j + 2], e3 = epk[j + 3];
    unsigned int v0 = x2[(e0 >> 16) * 64 + lane];
    unsigned int v1 = x2[(e1 >> 16) * 64 + lane];
    unsigned int v2 = x2[(e2 >> 16) * 64 + lane];
    unsigned int v3 = x2[(e3 >> 16) * 64 + lane];
    __half_raw h0, h1, h2, h3;
    h0.x = (unsigned short)(e0 & 0xffffu); h1.x = (unsigned short)(e1 & 0xffffu);
    h2.x = (unsigned short)(e2 & 0xffffu); h3.x = (unsigned short)(e3 & 0xffffu);
    float w0 = __half2float(h0), w1 = __half2float(h1);
    float w2 = __half2float(h2), w3 = __half2float(h3);
    ax0 = fmaf(__uint_as_float(v0 << 16), w0, ax0);
    ay0 = fmaf(__uint_as_float(v0 & 0xffff0000u), w0, ay0);
    ax1 = fmaf(__uint_as_float(v1 << 16), w1, ax1);
    ay1 = fmaf(__uint_as_float(v1 & 0xffff0000u), w1, ay1);
    ax2 = fmaf(__uint_as_float(v2 << 16), w2, ax2);
    ay2 = fmaf(__uint_as_float(v2 & 0xffff0000u), w2, ay2);
    ax3 = fmaf(__uint_as_float(v3 << 16), w3, ax3);
    ay3 = fmaf(__uint_as_float(v3 & 0xffff0000u), w3, ay3);
  }
  for (; j < end; ++j) {
    unsigned int e = epk[j];
    unsigned int v = x2[(e >> 16) * 64 + lane];
    __half_raw h; h.x = (unsigned short)(e & 0xffffu);
    float w = __half2float(h);
    ax0 = fmaf(__uint_as_float(v << 16), w, ax0);
    ay0 = fmaf(__uint_as_float(v & 0xffff0000u), w, ay0);
  }
  float2 acc = make_float2(ax0 + ax1 + ax2 + ax3, ay0 + ay1 + ay2 + ay3);
  ((float2*)agg)[n * 64 + lane] = acc;
}

// ---------------- MFMA hi/lo split helpers ----------------------------------
__device__ __forceinline__ void split8(const float* a, bf16x8& hi, bf16x8& lo) {
#pragma unroll
  for (int j = 0; j < 8; ++j) {
    float v = a[j];
    __bf16 h = (__bf16)v;
    hi[j] = h;
    lo[j] = (__bf16)(v - (float)h);
  }
}

// -------------------- GEMM1 (MFMA): h1 = (agg*nc + x) @ W1 + b1 + BN stats --
__launch_bounds__(128)
__global__ void k_gemm1(const float* __restrict__ agg, const float* __restrict__ nc,
                        const float* __restrict__ xin,
                        const __bf16* __restrict__ wtHi, const __bf16* __restrict__ wtLo,
                        const float* __restrict__ bias, float* __restrict__ out,
                        float* __restrict__ partial) {
  int tid = threadIdx.x;
  int w = tid >> 6, l = tid & 63;
  int row0 = blockIdx.x * 64;
  int l15 = l & 15, lg = l >> 4;
  int colw = w * 64;
  int krow = lg * 8;

  f32x4 acc[4][4];
#pragma unroll
  for (int m = 0; m < 4; ++m)
#pragma unroll
    for (int n = 0; n < 4; ++n) acc[m][n] = (f32x4){0.f, 0.f, 0.f, 0.f};

  int rowA[4]; bool rv[4]; float ncv[4];
#pragma unroll
  for (int m = 0; m < 4; ++m) {
    rowA[m] = row0 + m * 16 + l15;
    rv[m] = rowA[m] < Nn;
    ncv[m] = rv[m] ? nc[rowA[m]] : 0.f;
  }

#pragma unroll
  for (int ks = 0; ks < 4; ++ks) {
    int k0 = ks * 32 + krow;
    bf16x8 aHi[4], aLo[4];
#pragma unroll
    for (int m = 0; m < 4; ++m) {
      float av[8];
      if (rv[m]) {
        const float* ap = agg + rowA[m] * 128 + k0;
        const float* xp = xin + rowA[m] * 128 + k0;
        f32x4 g0 = *(const f32x4*)ap, g1 = *(const f32x4*)(ap + 4);
        f32x4 x0 = *(const f32x4*)xp, x1 = *(const f32x4*)(xp + 4);
#pragma unroll
        for (int jj = 0; jj < 4; ++jj) {
          av[jj]     = fmaf(g0[jj], ncv[m], x0[jj]);
          av[4 + jj] = fmaf(g1[jj], ncv[m], x1[jj]);
        }
      } else {
#pragma unroll
        for (int jj = 0; jj < 8; ++jj) av[jj] = 0.f;
      }
      split8(av, aHi[m], aLo[m]);
    }
    bf16x8 bHi[4], bLo[4];
#pragma unroll
    for (int n = 0; n < 4; ++n) {
      int c = colw + n * 16 + l15;
      bHi[n] = *(const bf16x8*)(wtHi + c * 128 + k0);
      bLo[n] = *(const bf16x8*)(wtLo + c * 128 + k0);
    }
#pragma unroll
    for (int m = 0; m < 4; ++m)
#pragma unroll
      for (int n = 0; n < 4; ++n) {
        acc[m][n] = __builtin_amdgcn_mfma_f32_16x16x32_bf16(aHi[m], bHi[n], acc[m][n], 0, 0, 0);
        acc[m][n] = __builtin_amdgcn_mfma_f32_16x16x32_bf16(aLo[m], bHi[n], acc[m][n], 0, 0, 0);
        acc[m][n] = __builtin_amdgcn_mfma_f32_16x16x32_bf16(aHi[m], bLo[n], acc[m][n], 0, 0, 0);
      }
  }

  // epilogue: bias, store, BN column stats
  float s[4] = {0.f, 0.f, 0.f, 0.f}, q[4] = {0.f, 0.f, 0.f, 0.f};
#pragma unroll
  for (int n = 0; n < 4; ++n) {
    int c = colw + n * 16 + l15;
    float bv = bias[c];
#pragma unroll
    for (int m = 0; m < 4; ++m) {
      int rbase = row0 + m * 16 + lg * 4;
#pragma unroll
      for (int r = 0; r < 4; ++r) {
        int rr = rbase + r;
        if (rr < Nn) {
          float o = acc[m][n][r] + bv;
          out[rr * 128 + c] = o;
          s[n] += o; q[n] += o * o;
        }
      }
    }
  }
#pragma unroll
  for (int n = 0; n < 4; ++n) {
    s[n] += __shfl_xor(s[n], 16, 64); q[n] += __shfl_xor(q[n], 16, 64);
    s[n] += __shfl_xor(s[n], 32, 64); q[n] += __shfl_xor(q[n], 32, 64);
  }
  if (lg == 0) {
    int blk = blockIdx.x;
#pragma unroll
    for (int n = 0; n < 4; ++n) {
      int f = colw + n * 16 + l15;
      partial[f * PPAD + blk] = s[n];
      partial[(128 + f) * PPAD + blk] = q[n];
    }
  }
}

// parallel partial reduce: one block per feature, coalesced strided reads.
__global__ void k_bnfin(const float* __restrict__ partial,
                        const float* __restrict__ g1, const float* __restrict__ be1,
                        float* __restrict__ scaleA, float* __restrict__ shiftA) {
  __shared__ float ss[256], qq[256];
  int f = blockIdx.x, t = threadIdx.x;
  float s = 0.f, q = 0.f;
  for (int b = t; b < NBLK1; b += 256) {
    s += partial[f * PPAD + b];
    q += partial[(128 + f) * PPAD + b];
  }
  ss[t] = s; qq[t] = q;
  __syncthreads();
  for (int off = 128; off > 0; off >>= 1) {
    if (t < off) { ss[t] += ss[t + off]; qq[t] += qq[t + off]; }
    __syncthreads();
  }
  if (t == 0) {
    const float inv = 1.0f / (float)Nn;
    float mu = ss[0] * inv;
    float var = fmaxf(qq[0] * inv - mu * mu, 0.f);
    float rs = rsqrtf(var + BN_EPS);
    float sc = rs * g1[f];
    scaleA[f] = sc;
    shiftA[f] = be1[f] - mu * sc;
  }
}

// ---- GEMM2 (MFMA): xout = relu( relu(h1*scaleA+shiftA) @ W2 + b2 ) ---------
// also writes bf16 copy of xout for the next layer's gather.
__launch_bounds__(128)
__global__ void k_gemm2(const float* __restrict__ h1, const float* __restrict__ scaleA,
                        const float* __restrict__ shiftA,
                        const __bf16* __restrict__ wtHi, const __bf16* __restrict__ wtLo,
                        const float* __restrict__ bias, float* __restrict__ out,
                        __bf16* __restrict__ xbout) {
  int tid = threadIdx.x;
  int w = tid >> 6, l = tid & 63;
  int row0 = blockIdx.x * 64;
  int l15 = l & 15, lg = l >> 4;
  int colw = w * 64;
  int krow = lg * 8;

  f32x4 acc[4][4];
#pragma unroll
  for (int m = 0; m < 4; ++m)
#pragma unroll
    for (int n = 0; n < 4; ++n) acc[m][n] = (f32x4){0.f, 0.f, 0.f, 0.f};

  int rowA[4]; bool rv[4];
#pragma unroll
  for (int m = 0; m < 4; ++m) {
    rowA[m] = row0 + m * 16 + l15;
    rv[m] = rowA[m] < Nn;
  }

#pragma unroll
  for (int ks = 0; ks < 4; ++ks) {
    int k0 = ks * 32 + krow;
    f32x4 sc0 = *(const f32x4*)(scaleA + k0), sc1 = *(const f32x4*)(scaleA + k0 + 4);
    f32x4 sh0 = *(const f32x4*)(shiftA + k0), sh1 = *(const f32x4*)(shiftA + k0 + 4);
    bf16x8 aHi[4], aLo[4];
#pragma unroll
    for (int m = 0; m < 4; ++m) {
      float av[8];
      if (rv[m]) {
        const float* hp = h1 + rowA[m] * 128 + k0;
        f32x4 h0 = *(const f32x4*)hp, h1v = *(const f32x4*)(hp + 4);
#pragma unroll
        for (int jj = 0; jj < 4; ++jj) {
          av[jj]     = fmaxf(fmaf(h0[jj],  sc0[jj], sh0[jj]), 0.f);
          av[4 + jj] = fmaxf(fmaf(h1v[jj], sc1[jj], sh1[jj]), 0.f);
        }
      } else {
#pragma unroll
        for (int jj = 0; jj < 8; ++jj) av[jj] = 0.f;
      }
      split8(av, aHi[m], aLo[m]);
    }
    bf16x8 bHi[4], bLo[4];
#pragma unroll
    for (int n = 0; n < 4; ++n) {
      int c = colw + n * 16 + l15;
      bHi[n] = *(const bf16x8*)(wtHi + c * 128 + k0);
      bLo[n] = *(const bf16x8*)(wtLo + c * 128 + k0);
    }
#pragma unroll
    for (int m = 0; m < 4; ++m)
#pragma unroll
      for (int n = 0; n < 4; ++n) {
        acc[m][n] = __builtin_amdgcn_mfma_f32_16x16x32_bf16(aHi[m], bHi[n], acc[m][n], 0, 0, 0);
        acc[m][n] = __builtin_amdgcn_mfma_f32_16x16x32_bf16(aLo[m], bHi[n], acc[m][n], 0, 0, 0);
        acc[m][n] = __builtin_amdgcn_mfma_f32_16x16x32_bf16(aHi[m], bLo[n], acc[m][n], 0, 0, 0);
      }
  }

#pragma unroll
  for (int n = 0; n < 4; ++n) {
    int c = colw + n * 16 + l15;
    float bv = bias[c];
#pragma unroll
    for (int m = 0; m < 4; ++m) {
      int rbase = row0 + m * 16 + lg * 4;
#pragma unroll
      for (int r = 0; r < 4; ++r) {
        int rr = rbase + r;
        if (rr < Nn) {
          float o = fmaxf(acc[m][n][r] + bv, 0.f);
          out[rr * 128 + c] = o;
          xbout[rr * 128 + c] = (__bf16)o;
        }
      }
    }
  }
}

// ------------------------------ pooling -------------------------------------
#define PCH 64
__global__ void k_pool(const float* __restrict__ xin, const int* __restrict__ batch,
                       float* __restrict__ pooled, float* __restrict__ gcnt) {
  int wid = threadIdx.x >> 6, lane = threadIdx.x & 63;
  int w = blockIdx.x * 4 + wid;
  int n0 = w * PCH;
  if (n0 >= Nn) return;
  int n1 = (n0 + PCH < Nn) ? n0 + PCH : Nn;
  const float2* x2 = (const float2*)xin;
  float2 acc = make_float2(0.f, 0.f);
  int cur = batch[n0];
  int cnt = 0;
  for (int n = n0; n < n1; ++n) {
    int g = batch[n];                    // wave-uniform
    if (g != cur) {
      atomicAdd(&pooled[cur * 128 + lane * 2 + 0], acc.x);
      atomicAdd(&pooled[cur * 128 + lane * 2 + 1], acc.y);
      if (lane == 0) atomicAdd(&gcnt[cur], (float)cnt);
      acc = make_float2(0.f, 0.f); cnt = 0; cur = g;
    }
    float2 v = x2[n * 64 + lane];
    acc.x += v.x; acc.y += v.y; ++cnt;
  }
  atomicAdd(&pooled[cur * 128 + lane * 2 + 0], acc.x);
  atomicAdd(&pooled[cur * 128 + lane * 2 + 1], acc.y);
  if (lane == 0) atomicAdd(&gcnt[cur], (float)cnt);
}

__global__ void k_head(const float* __restrict__ pooled, const float* __restrict__ gcnt,
                       const float* __restrict__ Wc, const float* __restrict__ bc,
                       float* __restrict__ out) {
  __shared__ float p[128];
  int g = blockIdx.x, tid = threadIdx.x;
  p[tid] = pooled[g * 128 + tid] / fmaxf(gcnt[g], 1.0f);
  __syncthreads();
  if (tid < Cc) {
    float acc = bc[tid];
    for (int k = 0; k < 128; ++k) acc = fmaf(p[k], Wc[k * Cc + tid], acc);
    out[g * Cc + tid] = acc;
  }
}

// ------------------------------ launcher ------------------------------------
extern "C" void kernel_launch(void* const* d_in, const int* in_sizes, int n_in,
                              void* d_out, int out_size, void* d_ws, size_t ws_size,
                              hipStream_t stream) {
  const float* x    = (const float*)d_in[0];
  const float* ncn  = (const float*)d_in[1];
  const float* ecn  = (const float*)d_in[2];
  const float* W1   = (const float*)d_in[3];
  const float* b1   = (const float*)d_in[4];
  const float* g1   = (const float*)d_in[5];
  const float* be1  = (const float*)d_in[6];
  const float* W2   = (const float*)d_in[7];
  const float* b2   = (const float*)d_in[8];
  const float* Wc   = (const float*)d_in[9];
  const float* bc   = (const float*)d_in[10];
  const int*   ei   = (const int*)d_in[11];
  const int*   batch= (const int*)d_in[12];
  const int* src  = ei;
  const int* dstp = ei + Ee;

  float* fws = (float*)d_ws;
  float* bufA     = fws;                       // N*128
  float* bufB     = fws +  6400000;            // N*128
  float* h1       = fws + 12800000;            // N*128 (fixed)
  float* partial  = fws + 19200000;            // 256*PPAD (800 KB)
  float* scaleA   = partial + 256 * PPAD;      // 128
  float* shiftA   = scaleA + 128;              // 128
  float* pooled   = shiftA + 128;              // G*128
  float* gcnt     = pooled + Gg * 128;         // 128
  int*   ib       = (int*)(gcnt + 128);
  int*   deg      = ib;                        // N
  int*   offs     = deg + Nn;                  // N+64
  int*   cursor   = offs + Nn + 64;            // N
  int*   bsum     = cursor + Nn;               // 64
  int*   carry    = bsum + 64;                 // 64
  unsigned int* epk = (unsigned int*)(carry + 64); // E  (4B packed edges)
  __bf16* wtHi    = (__bf16*)(epk + Ee);       // 6*16384 bf16
  __bf16* wtLo    = wtHi + 6 * 16384;          // 6*16384 bf16
  __bf16* xb      = wtLo + 6 * 16384;          // N*128 bf16 (12.8 MB)

  // W prep + x cast + CSR build (once per call, reused by all 3 layers)
  k_wprep<<<48, 256, 0, stream>>>(W1, W2, wtHi, wtLo);
  k_xcast<<<2048, 256, 0, stream>>>(x, xb);
  hipMemsetAsync(deg, 0, Nn * sizeof(int), stream);
  k_deg<<<(Ee / 4 + 255) / 256, 256, 0, stream>>>(dstp, deg);
  k_scan1<<<NSCB, 1024, 0, stream>>>(deg, offs, bsum);
  k_scan2<<<1, 64, 0, stream>>>(bsum, carry);
  k_scan3<<<NSCB, 1024, 0, stream>>>(carry, offs, cursor);
  k_fill<<<(Ee / 4 + 255) / 256, 256, 0, stream>>>(src, dstp, ecn, cursor, epk);

  // Buffer schedule (agg dead after gemm1 -> gemm2 overwrites it; xb is
  // consumed by k_agg before gemm2 overwrites it with the next layer's input)
  const float* xin = x;
  for (int l = 0; l < Ll; ++l) {
    float* aggb = (l & 1) ? bufB : bufA;
    k_agg<<<(Nn + 3) / 4, 256, 0, stream>>>(xb, offs, epk, aggb);
    k_gemm1<<<NBLK1, 128, 0, stream>>>(aggb, ncn, xin,
                                       wtHi + l * 16384, wtLo + l * 16384,
                                       b1 + l * 128, h1, partial);
    k_bnfin<<<128, 256, 0, stream>>>(partial, g1 + l * 128, be1 + l * 128,
                                     scaleA, shiftA);
    k_gemm2<<<NBLK1, 128, 0, stream>>>(h1, scaleA, shiftA,
                                       wtHi + (3 + l) * 16384, wtLo + (3 + l) * 16384,
                                       b2 + l * 128, aggb, xb);
    xin = aggb;
  }

  hipMemsetAsync(pooled, 0, (Gg * 128 + 128) * sizeof(float), stream);
  k_pool<<<(Nn + PCH * 4 - 1) / (PCH * 4), 256, 0, stream>>>(xin, batch, pooled, gcnt);
  k_head<<<Gg, 128, 0, stream>>>(pooled, gcnt, Wc, bc, (float*)d_out);
}